// Round 1
// baseline (526.608 us; speedup 1.0000x reference)
//
#include <hip/hip_runtime.h>
#include <cstdint>
#include <cstddef>

// ---------------------------------------------------------------------------
// Generic fp32 GEMM: Y[M x NC] = act(X[M x K] @ W[K x NC] + bias)
// Tile: 64 rows x BN cols per block (BN = 16*TN), 256 threads, 4xTN micro-tile.
// W is indexed W[k*wld + col0 + n]; Y is Y[row*yld + col0 + n].
// ---------------------------------------------------------------------------
template<int K, int TN, bool RELU, bool HASBIAS>
__global__ __launch_bounds__(256) void gemm_k(
    const float* __restrict__ X, const float* __restrict__ W, int wld,
    const float* __restrict__ bias, float* __restrict__ Y, int yld)
{
    constexpr int BN = 16 * TN;
    __shared__ float at[16][68];        // [k][row], padded
    __shared__ float bt[16][BN + 4];    // [k][col], padded
    const int row0 = blockIdx.x * 64;
    const int col0 = blockIdx.y * BN;
    const int tid  = threadIdx.x;
    const int tr   = tid >> 4;          // 0..15
    const int tc   = tid & 15;          // 0..15

    float acc[4][TN];
#pragma unroll
    for (int i = 0; i < 4; i++)
#pragma unroll
        for (int j = 0; j < TN; j++) acc[i][j] = 0.f;

    for (int kk = 0; kk < K; kk += 16) {
        // stage A: 64 rows x 16 k (transposed into LDS as [k][row])
        {
            const int r  = tid >> 2;            // 0..63
            const int k4 = (tid & 3) << 2;      // 0,4,8,12
            const float4 v = *reinterpret_cast<const float4*>(
                X + (size_t)(row0 + r) * K + kk + k4);
            at[k4 + 0][r] = v.x; at[k4 + 1][r] = v.y;
            at[k4 + 2][r] = v.z; at[k4 + 3][r] = v.w;
        }
        // stage B: 16 k x BN cols
#pragma unroll
        for (int i = tid; i < 16 * BN; i += 256) {
            const int k = i / BN, n = i % BN;
            bt[k][n] = W[(size_t)(kk + k) * wld + col0 + n];
        }
        __syncthreads();
#pragma unroll
        for (int k2 = 0; k2 < 16; k2++) {
            float a[4], b[TN];
            const float4 av = *reinterpret_cast<const float4*>(&at[k2][tr * 4]);
            a[0] = av.x; a[1] = av.y; a[2] = av.z; a[3] = av.w;
#pragma unroll
            for (int j = 0; j < TN; j++) b[j] = bt[k2][tc * TN + j];
#pragma unroll
            for (int i = 0; i < 4; i++)
#pragma unroll
                for (int j = 0; j < TN; j++)
                    acc[i][j] = fmaf(a[i], b[j], acc[i][j]);
        }
        __syncthreads();
    }

#pragma unroll
    for (int i = 0; i < 4; i++) {
        const size_t r = (size_t)(row0 + tr * 4 + i);
#pragma unroll
        for (int j = 0; j < TN; j++) {
            const int c = col0 + tc * TN + j;
            float v = acc[i][j];
            if (HASBIAS) v += bias[c];
            if (RELU)    v = fmaxf(v, 0.f);
            Y[r * yld + c] = v;
        }
    }
}

// ---------------------------------------------------------------------------
// P[t,h] = pe[t+1] @ Wc1[128:144,:] + pe[t] @ Wc1[272:288,:] + bc1,  t=0..254
// pe[t,2i] = sin(t*div_i), pe[t,2i+1] = cos(t*div_i), div_i = 10000^(-i/8)
// ---------------------------------------------------------------------------
__global__ void pe_kernel(const float* __restrict__ Wc1,
                          const float* __restrict__ bc1,
                          float* __restrict__ P)
{
    const int idx = blockIdx.x * 256 + threadIdx.x;
    if (idx >= 255 * 288) return;
    const int t = idx / 288, ho = idx % 288;
    float acc = bc1[ho];
#pragma unroll
    for (int i = 0; i < 8; i++) {
        const float div = expf(-1.1512925464970229f * (float)i); // ln(10000)/8
        const float a1 = (float)(t + 1) * div;
        const float a0 = (float)t * div;
        acc += sinf(a1) * Wc1[(size_t)(128 + 2 * i) * 288 + ho];
        acc += cosf(a1) * Wc1[(size_t)(129 + 2 * i) * 288 + ho];
        acc += sinf(a0) * Wc1[(size_t)(272 + 2 * i) * 288 + ho];
        acc += cosf(a0) * Wc1[(size_t)(273 + 2 * i) * 288 + ho];
    }
    P[idx] = acc;
}

// ---------------------------------------------------------------------------
// Final: out[b,t,e,c] = relu(S[b,t+1,se[e],:] + R[b,t,re[e],:] + P[t,:]) @ Wc2 + bc2
// One wave per edge (8 edges sequential per wave), Wc2^T + P[t] in LDS.
// grid = 510 * 32 blocks; block = 256 threads (4 waves).
// ---------------------------------------------------------------------------
__global__ __launch_bounds__(256) void final_kernel(
    const float* __restrict__ S, const float* __restrict__ R,
    const float* __restrict__ P, const float* __restrict__ Wc2,
    const float* __restrict__ bc2, const int* __restrict__ se,
    const int* __restrict__ re, float* __restrict__ out)
{
    __shared__ float wc2[5][288];
    __shared__ float pl[288];
    __shared__ float bb[5];
    const int bt  = blockIdx.x >> 5;    // 0..509
    const int eg  = blockIdx.x & 31;    // edge group (32 edges)
    const int b   = bt / 255;
    const int t   = bt % 255;
    const int tid = threadIdx.x;

    for (int i = tid; i < 288 * 5; i += 256) wc2[i % 5][i / 5] = Wc2[i];
    for (int i = tid; i < 288; i += 256)     pl[i] = P[(size_t)t * 288 + i];
    if (tid < 5) bb[tid] = bc2[tid];
    __syncthreads();

    const int w = tid >> 6, l = tid & 63;
    const float* Sbase = S + (size_t)((b * 256 + t + 1) * 128) * 288;
    const float* Rbase = R + (size_t)((b * 256 + t) * 128) * 288;

    for (int it = 0; it < 8; it++) {
        const int e = eg * 32 + w * 8 + it;
        const float* Sp = Sbase + (size_t)se[e] * 288;
        const float* Rp = Rbase + (size_t)re[e] * 288;
        float a0 = 0.f, a1 = 0.f, a2 = 0.f, a3 = 0.f, a4 = 0.f;
#pragma unroll
        for (int j = 0; j < 5; j++) {
            const int h = j * 64 + l;
            if (h < 288) {
                const float v = fmaxf(Sp[h] + Rp[h] + pl[h], 0.f);
                a0 = fmaf(v, wc2[0][h], a0);
                a1 = fmaf(v, wc2[1][h], a1);
                a2 = fmaf(v, wc2[2][h], a2);
                a3 = fmaf(v, wc2[3][h], a3);
                a4 = fmaf(v, wc2[4][h], a4);
            }
        }
#pragma unroll
        for (int off = 32; off > 0; off >>= 1) {
            a0 += __shfl_down(a0, off);
            a1 += __shfl_down(a1, off);
            a2 += __shfl_down(a2, off);
            a3 += __shfl_down(a3, off);
            a4 += __shfl_down(a4, off);
        }
        if (l == 0) {
            float* op = out + ((size_t)(b * 255 + t) * 1024 + e) * 5;
            op[0] = a0 + bb[0]; op[1] = a1 + bb[1]; op[2] = a2 + bb[2];
            op[3] = a3 + bb[3]; op[4] = a4 + bb[4];
        }
    }
}

// ---------------------------------------------------------------------------
extern "C" void kernel_launch(void* const* d_in, const int* in_sizes, int n_in,
                              void* d_out, int out_size, void* d_ws, size_t ws_size,
                              hipStream_t stream)
{
    const float* spikes = (const float*)d_in[0];   // (2,256,128,16)
    const float* W_emb  = (const float*)d_in[1];   // (16,128)
    const float* b_emb  = (const float*)d_in[2];
    const float* Ws1    = (const float*)d_in[3];
    const float* bs1    = (const float*)d_in[4];
    const float* Ws2    = (const float*)d_in[5];
    const float* bs2    = (const float*)d_in[6];
    const float* Wr1    = (const float*)d_in[7];
    const float* br1    = (const float*)d_in[8];
    const float* Wr2    = (const float*)d_in[9];
    const float* br2    = (const float*)d_in[10];
    const float* Wc1    = (const float*)d_in[11];  // (288,288)
    const float* bc1    = (const float*)d_in[12];
    const float* Wc2    = (const float*)d_in[13];  // (288,5)
    const float* bc2    = (const float*)d_in[14];
    const int*   se     = (const int*)d_in[15];    // (1024,)
    const int*   re     = (const int*)d_in[16];

    float* out = (float*)d_out;
    float* ws  = (float*)d_ws;

    // workspace layout (floats):
    // [send 8.39M][recv 8.39M][S 18.87M][R 18.87M][P 73440]  = 218.4 MB
    // emb aliases S's region (dead before S is written),
    // tmp aliases R's region (dead before R is written).
    float* send = ws;
    float* recv = ws + 8388608;
    float* S    = ws + 16777216;
    float* R    = ws + 35651584;
    float* P    = ws + 54525952;
    float* emb  = S;
    float* tmp  = R;

    const dim3 blk(256);
    // emb = spikes @ W_emb + b_emb                  (M=65536, K=16,  N=128)
    gemm_k<16, 4, false, true><<<dim3(1024, 2), blk, 0, stream>>>(
        spikes, W_emb, 128, b_emb, emb, 128);
    // send chain
    gemm_k<128, 4, true, true><<<dim3(1024, 2), blk, 0, stream>>>(
        emb, Ws1, 128, bs1, tmp, 128);
    gemm_k<128, 4, true, true><<<dim3(1024, 2), blk, 0, stream>>>(
        tmp, Ws2, 128, bs2, send, 128);
    // recv chain
    gemm_k<128, 4, true, true><<<dim3(1024, 2), blk, 0, stream>>>(
        emb, Wr1, 128, br1, tmp, 128);
    gemm_k<128, 4, true, true><<<dim3(1024, 2), blk, 0, stream>>>(
        tmp, Wr2, 128, br2, recv, 128);
    // S = send @ Wc1[0:128,:]    (N=288, no bias/relu)
    gemm_k<128, 3, false, false><<<dim3(1024, 6), blk, 0, stream>>>(
        send, Wc1, 288, nullptr, S, 288);
    // R = recv @ Wc1[144:272,:]
    gemm_k<128, 3, false, false><<<dim3(1024, 6), blk, 0, stream>>>(
        recv, Wc1 + (size_t)144 * 288, 288, nullptr, R, 288);
    // P[t,:] (positional-encoding contribution + bc1)
    pe_kernel<<<287, blk, 0, stream>>>(Wc1, bc1, P);
    // gather + relu + head
    final_kernel<<<510 * 32, blk, 0, stream>>>(S, R, P, Wc2, bc2, se, re, out);
}

// Round 2
// 392.111 us; speedup vs baseline: 1.3430x; 1.3430x over previous
//
#include <hip/hip_runtime.h>
#include <cstdint>
#include <cstddef>

typedef __attribute__((ext_vector_type(8))) short bf16x8;
typedef __attribute__((ext_vector_type(4))) float f32x4;

__device__ inline float bfu2f(unsigned short u) {
    union { unsigned u; float f; } c; c.u = ((unsigned)u) << 16; return c.f;
}
__device__ inline unsigned short f2bfu(float f) {  // RNE pack (finite values)
    union { float f; unsigned u; } c; c.f = f;
    unsigned r = c.u + 0x7FFFu + ((c.u >> 16) & 1u);
    return (unsigned short)(r >> 16);
}

// ---------------------------------------------------------------------------
// Generic fp32 GEMM: Y[M x NC] = act(X[M x K] @ W[K x NC] + bias [+ P])
// Tile: 64 rows x BN cols (BN = 16*TN), 256 threads, 4xTN micro-tile.
// OUT_BF16: store Y as bf16 (ushort). ADD_P: Y += P[t*288+c], t=(row>>7)&255.
// ---------------------------------------------------------------------------
template<int K, int TN, bool RELU, bool HASBIAS, bool OUT_BF16, bool ADD_P>
__global__ __launch_bounds__(256) void gemm_k(
    const float* __restrict__ X, const float* __restrict__ W, int wld,
    const float* __restrict__ bias, const float* __restrict__ Pp,
    void* __restrict__ Yv, int yld)
{
    constexpr int BN = 16 * TN;
    __shared__ float at[16][68];
    __shared__ float bt[16][BN + 4];
    const int row0 = blockIdx.x * 64;
    const int col0 = blockIdx.y * BN;
    const int tid  = threadIdx.x;
    const int tr   = tid >> 4;
    const int tc   = tid & 15;

    float acc[4][TN];
#pragma unroll
    for (int i = 0; i < 4; i++)
#pragma unroll
        for (int j = 0; j < TN; j++) acc[i][j] = 0.f;

    for (int kk = 0; kk < K; kk += 16) {
        {
            const int r  = tid >> 2;
            const int k4 = (tid & 3) << 2;
            const float4 v = *reinterpret_cast<const float4*>(
                X + (size_t)(row0 + r) * K + kk + k4);
            at[k4 + 0][r] = v.x; at[k4 + 1][r] = v.y;
            at[k4 + 2][r] = v.z; at[k4 + 3][r] = v.w;
        }
#pragma unroll
        for (int i = tid; i < 16 * BN; i += 256) {
            const int k = i / BN, n = i % BN;
            bt[k][n] = W[(size_t)(kk + k) * wld + col0 + n];
        }
        __syncthreads();
#pragma unroll
        for (int k2 = 0; k2 < 16; k2++) {
            float a[4], b[TN];
            const float4 av = *reinterpret_cast<const float4*>(&at[k2][tr * 4]);
            a[0] = av.x; a[1] = av.y; a[2] = av.z; a[3] = av.w;
#pragma unroll
            for (int j = 0; j < TN; j++) b[j] = bt[k2][tc * TN + j];
#pragma unroll
            for (int i = 0; i < 4; i++)
#pragma unroll
                for (int j = 0; j < TN; j++)
                    acc[i][j] = fmaf(a[i], b[j], acc[i][j]);
        }
        __syncthreads();
    }

#pragma unroll
    for (int i = 0; i < 4; i++) {
        const int r = row0 + tr * 4 + i;
        const int tt = (r >> 7) & 255;
#pragma unroll
        for (int j = 0; j < TN; j++) {
            const int c = col0 + tc * TN + j;
            float v = acc[i][j];
            if (HASBIAS) v += bias[c];
            if (ADD_P)   { if (tt < 255) v += Pp[(size_t)tt * 288 + c]; }
            if (RELU)    v = fmaxf(v, 0.f);
            if (OUT_BF16)
                ((unsigned short*)Yv)[(size_t)r * yld + c] = f2bfu(v);
            else
                ((float*)Yv)[(size_t)r * yld + c] = v;
        }
    }
}

// ---------------------------------------------------------------------------
// P[t,h] = pe[t+1] @ Wc1[128:144,:] + pe[t] @ Wc1[272:288,:] + bc1,  t=0..254
// ---------------------------------------------------------------------------
__global__ void pe_kernel(const float* __restrict__ Wc1,
                          const float* __restrict__ bc1,
                          float* __restrict__ P)
{
    const int idx = blockIdx.x * 256 + threadIdx.x;
    if (idx >= 255 * 288) return;
    const int t = idx / 288, ho = idx % 288;
    float acc = bc1[ho];
#pragma unroll
    for (int i = 0; i < 8; i++) {
        const float div = expf(-1.1512925464970229f * (float)i); // ln(10000)/8
        const float a1 = (float)(t + 1) * div;
        const float a0 = (float)t * div;
        acc += sinf(a1) * Wc1[(size_t)(128 + 2 * i) * 288 + ho];
        acc += cosf(a1) * Wc1[(size_t)(129 + 2 * i) * 288 + ho];
        acc += sinf(a0) * Wc1[(size_t)(272 + 2 * i) * 288 + ho];
        acc += cosf(a0) * Wc1[(size_t)(273 + 2 * i) * 288 + ho];
    }
    P[idx] = acc;
}

// ---------------------------------------------------------------------------
// Wc2 (288x5 fp32) -> bf16 B-fragments, padded to 16 cols, fragment order:
// wc2f[ks*512 + l*8 + j] = Wc2[k][c], k = ks*32 + (l>>4)*8 + j, c = l&15 (<5)
// ---------------------------------------------------------------------------
__global__ void prep_wc2(const float* __restrict__ Wc2,
                         unsigned short* __restrict__ wc2f)
{
    const int i = blockIdx.x * 256 + threadIdx.x;
    if (i >= 9 * 64 * 8) return;
    const int j = i & 7, l = (i >> 3) & 63, ks = i >> 9;
    const int k = ks * 32 + (l >> 4) * 8 + j;
    const int c = l & 15;
    wc2f[i] = (c < 5) ? f2bfu(Wc2[(size_t)k * 5 + c]) : (unsigned short)0;
}

// ---------------------------------------------------------------------------
// Final: out[bt,e,c] = relu(S[b,t+1,se[e],:] + R'[b,t,re[e],:]) @ Wc2 + bc2
// (P and bc1 already folded into R'.)  One wave per 16-edge tile, 9 MFMA
// 16x16x32 bf16 per tile; zero LDS, zero shuffles.
// grid = 2040 blocks x 256 thr; each wave does 4 tiles.
// ---------------------------------------------------------------------------
__global__ __launch_bounds__(256) void final_mfma(
    const unsigned short* __restrict__ S, const unsigned short* __restrict__ R,
    const unsigned short* __restrict__ wc2f, const float* __restrict__ bc2,
    const int* __restrict__ se, const int* __restrict__ re,
    float* __restrict__ out)
{
    // XCD swizzle: 2040 = 8*255; give each XCD a contiguous run of (b,t) slices
    const int bid  = blockIdx.x;
    const int task = (bid & 7) * 255 + (bid >> 3);
    const int bt = task >> 2, tg = task & 3;         // bt 0..509, tg 0..3
    const int b = bt / 255, t = bt % 255;
    const int tid = threadIdx.x, w = tid >> 6, l = tid & 63;
    const int lm = l & 15, lk = l >> 4;

    bf16x8 bfrag[9];
#pragma unroll
    for (int ks = 0; ks < 9; ks++)
        bfrag[ks] = *reinterpret_cast<const bf16x8*>(wc2f + (ks * 64 + l) * 8);

    const float bias = (lm < 5) ? bc2[lm] : 0.f;

    const unsigned short* Sb = S + (size_t)((b * 256 + t + 1) * 128) * 288 + lk * 8;
    const unsigned short* Rb = R + (size_t)((b * 256 + t) * 128) * 288 + lk * 8;

    for (int it = 0; it < 4; it++) {
        const int tile = tg * 16 + w * 4 + it;       // 0..63
        const int e0 = tile * 16;
        const unsigned short* Srow = Sb + (size_t)se[e0 + lm] * 288;
        const unsigned short* Rrow = Rb + (size_t)re[e0 + lm] * 288;
        f32x4 acc = {0.f, 0.f, 0.f, 0.f};
#pragma unroll
        for (int ks = 0; ks < 9; ks++) {
            const bf16x8 s8 = *reinterpret_cast<const bf16x8*>(Srow + ks * 32);
            const bf16x8 r8 = *reinterpret_cast<const bf16x8*>(Rrow + ks * 32);
            bf16x8 h;
#pragma unroll
            for (int j = 0; j < 8; j++) {
                const float v = bfu2f((unsigned short)s8[j]) +
                                bfu2f((unsigned short)r8[j]);
                h[j] = (short)f2bfu(fmaxf(v, 0.f));
            }
            acc = __builtin_amdgcn_mfma_f32_16x16x32_bf16(h, bfrag[ks], acc, 0, 0, 0);
        }
        if (lm < 5) {
            float* op = out + ((size_t)bt * 1024 + e0 + lk * 4) * 5 + lm;
            op[0]  = acc[0] + bias;
            op[5]  = acc[1] + bias;
            op[10] = acc[2] + bias;
            op[15] = acc[3] + bias;
        }
    }
}

// ---------------------------------------------------------------------------
extern "C" void kernel_launch(void* const* d_in, const int* in_sizes, int n_in,
                              void* d_out, int out_size, void* d_ws, size_t ws_size,
                              hipStream_t stream)
{
    const float* spikes = (const float*)d_in[0];
    const float* W_emb  = (const float*)d_in[1];
    const float* b_emb  = (const float*)d_in[2];
    const float* Ws1    = (const float*)d_in[3];
    const float* bs1    = (const float*)d_in[4];
    const float* Ws2    = (const float*)d_in[5];
    const float* bs2    = (const float*)d_in[6];
    const float* Wr1    = (const float*)d_in[7];
    const float* br1    = (const float*)d_in[8];
    const float* Wr2    = (const float*)d_in[9];
    const float* br2    = (const float*)d_in[10];
    const float* Wc1    = (const float*)d_in[11];
    const float* bc1    = (const float*)d_in[12];
    const float* Wc2    = (const float*)d_in[13];
    const float* bc2    = (const float*)d_in[14];
    const int*   se     = (const int*)d_in[15];
    const int*   re     = (const int*)d_in[16];

    float* out = (float*)d_out;
    float* ws  = (float*)d_ws;

    // workspace (floats):
    float* send = ws;                                  //  8,388,608
    float* recv = ws + 8388608;                        //  8,388,608
    float* emb  = ws + 16777216;                       //  8,388,608
    float* tmp  = ws + 25165824;                       //  8,388,608
    unsigned short* S16  = (unsigned short*)(ws + 33554432);  // 18,874,368 u16
    unsigned short* R16  = (unsigned short*)(ws + 42991616);  // 18,874,368 u16
    float* P    = ws + 52428800;                       //     73,440
    unsigned short* wc2f = (unsigned short*)(ws + 52502240);  // 4,608 u16

    const dim3 blk(256);

    // P (needed by R-GEMM epilogue) and Wc2 fragments
    pe_kernel<<<287, blk, 0, stream>>>(Wc1, bc1, P);
    prep_wc2<<<18, blk, 0, stream>>>(Wc2, wc2f);

    // emb = spikes @ W_emb + b_emb
    gemm_k<16, 4, false, true, false, false><<<dim3(1024, 2), blk, 0, stream>>>(
        spikes, W_emb, 128, b_emb, nullptr, emb, 128);
    // send chain
    gemm_k<128, 4, true, true, false, false><<<dim3(1024, 2), blk, 0, stream>>>(
        emb, Ws1, 128, bs1, nullptr, tmp, 128);
    gemm_k<128, 4, true, true, false, false><<<dim3(1024, 2), blk, 0, stream>>>(
        tmp, Ws2, 128, bs2, nullptr, send, 128);
    // recv chain
    gemm_k<128, 4, true, true, false, false><<<dim3(1024, 2), blk, 0, stream>>>(
        emb, Wr1, 128, br1, nullptr, tmp, 128);
    gemm_k<128, 4, true, true, false, false><<<dim3(1024, 2), blk, 0, stream>>>(
        tmp, Wr2, 128, br2, nullptr, recv, 128);
    // S = send @ Wc1[0:128,:]          -> bf16
    gemm_k<128, 3, false, false, true, false><<<dim3(1024, 6), blk, 0, stream>>>(
        send, Wc1, 288, nullptr, nullptr, S16, 288);
    // R' = recv @ Wc1[144:272,:] + P   -> bf16
    gemm_k<128, 3, false, false, true, true><<<dim3(1024, 6), blk, 0, stream>>>(
        recv, Wc1 + (size_t)144 * 288, 288, nullptr, P, R16, 288);
    // gather + relu + head via MFMA
    final_mfma<<<2040, blk, 0, stream>>>(S16, R16, wc2f, bc2, se, re, out);
}

// Round 3
// 155.146 us; speedup vs baseline: 3.3943x; 2.5274x over previous
//
#include <hip/hip_runtime.h>
#include <cstdint>
#include <cstddef>

typedef __attribute__((ext_vector_type(8))) short bf16x8;
typedef __attribute__((ext_vector_type(4))) float f32x4;

__device__ inline unsigned short f2bfu(float f) {  // RNE pack (finite values)
    union { float f; unsigned u; } c; c.f = f;
    unsigned r = c.u + 0x7FFFu + ((c.u >> 16) & 1u);
    return (unsigned short)(r >> 16);
}

// ---------------------------------------------------------------------------
// One-shot prep: P (PE@Wc1 + bc1), folded first-layer weights/biases, and all
// weights converted to bf16 in MFMA B-fragment order:
//   frag[f*512 + l*8 + j] = W[ks*32 + (l>>4)*8 + j][nf*16 + (l&15)]
// ---------------------------------------------------------------------------
__global__ void prep_kernel(
    const float* __restrict__ W_emb, const float* __restrict__ b_emb,
    const float* __restrict__ Ws1, const float* __restrict__ bs1,
    const float* __restrict__ Wr1, const float* __restrict__ br1,
    const float* __restrict__ Ws2, const float* __restrict__ bs2,
    const float* __restrict__ Wr2, const float* __restrict__ br2,
    const float* __restrict__ Wc1, const float* __restrict__ bc1,
    const float* __restrict__ Wc2,
    float* __restrict__ P, float* __restrict__ bias1, float* __restrict__ bias2,
    unsigned short* __restrict__ wg1f, unsigned short* __restrict__ wg2f,
    unsigned short* __restrict__ wg3f, unsigned short* __restrict__ wc2f)
{
    int id = blockIdx.x * 256 + threadIdx.x;

    if (id < 73440) {   // P[t,h] = pe[t+1]@Wc1[128:144] + pe[t]@Wc1[272:288] + bc1
        const int t = id / 288, ho = id % 288;
        float acc = bc1[ho];
#pragma unroll
        for (int i = 0; i < 8; i++) {
            const float div = expf(-1.1512925464970229f * (float)i);
            const float a1 = (float)(t + 1) * div;
            const float a0 = (float)t * div;
            acc += sinf(a1) * Wc1[(size_t)(128 + 2 * i) * 288 + ho];
            acc += cosf(a1) * Wc1[(size_t)(129 + 2 * i) * 288 + ho];
            acc += sinf(a0) * Wc1[(size_t)(272 + 2 * i) * 288 + ho];
            acc += cosf(a0) * Wc1[(size_t)(273 + 2 * i) * 288 + ho];
        }
        P[id] = acc;
        return;
    }
    id -= 73440;

    if (id < 8192) {    // wg1f: [W_emb@Ws1 | W_emb@Wr1], K padded 16->32
        const int y = id >> 12, r = id & 4095;
        const int f = r >> 9, l = (r >> 3) & 63, j = r & 7;
        const int k = ((l >> 4) << 3) + j;          // 0..31
        const int n = f * 16 + (l & 15);
        float v = 0.f;
        if (k < 16) {
            const float* Wx = y ? Wr1 : Ws1;
            for (int d = 0; d < 128; d++) v += W_emb[k * 128 + d] * Wx[d * 128 + n];
        }
        wg1f[id] = f2bfu(v);
        return;
    }
    id -= 8192;

    if (id < 256) {     // bias1 = [bs1 + b_emb@Ws1 | br1 + b_emb@Wr1]
        const int y = id >> 7, c = id & 127;
        const float* Wx = y ? Wr1 : Ws1;
        float v = (y ? br1 : bs1)[c];
        for (int d = 0; d < 128; d++) v += b_emb[d] * Wx[d * 128 + c];
        bias1[id] = v;
        return;
    }
    id -= 256;

    if (id < 32768) {   // wg2f: [Ws2 | Wr2] fragments
        const int y = id >> 14, r = id & 16383;
        const int f = r >> 9, l = (r >> 3) & 63, j = r & 7;
        const int ks = f >> 3, nf = f & 7;
        const int k = ks * 32 + ((l >> 4) << 3) + j;
        const int n = nf * 16 + (l & 15);
        wg2f[id] = f2bfu((y ? Wr2 : Ws2)[(size_t)k * 128 + n]);
        return;
    }
    id -= 32768;

    if (id < 256) {     // bias2 = [bs2 | br2]
        bias2[id] = (id < 128) ? bs2[id] : br2[id - 128];
        return;
    }
    id -= 256;

    if (id < 73728) {   // wg3f: [Wc1[0:128,:] | Wc1[144:272,:]] fragments
        const int y = id / 36864, r = id % 36864;
        const int f = r >> 9, l = (r >> 3) & 63, j = r & 7;
        const int ks = f / 18, nf = f % 18;
        const int k = ks * 32 + ((l >> 4) << 3) + j;
        const int n = nf * 16 + (l & 15);
        wg3f[id] = f2bfu(Wc1[(size_t)(y * 144 + k) * 288 + n]);
        return;
    }
    id -= 73728;

    if (id < 4608) {    // wc2f: head weight fragments (288x5 padded to 16 cols)
        const int j = id & 7, l = (id >> 3) & 63, ks = id >> 9;
        const int k = ks * 32 + ((l >> 4) << 3) + j;
        const int c = l & 15;
        wc2f[id] = (c < 5) ? f2bfu(Wc2[(size_t)k * 5 + c]) : (unsigned short)0;
    }
}

// ---------------------------------------------------------------------------
// bf16 MFMA GEMM, no LDS. Block = 64 rows x (NFRAGS*32) cols, 4 waves (2x2).
// Wave = 32 rows x (NFRAGS*16) cols; A-frags per-lane from global (L1/L2),
// B-frags from prepped fragment arrays (L2-resident).
// blockIdx.y selects the weight block (block-diagonal fusion) and A k-offset.
// A_F32K16: A is fp32 with K=16 (padded to 32 with zeros in-register).
// ADD_P: y==1 half adds P[t*288 + (gc-288)] (t = (row>>7)&255, skip t==255).
// ---------------------------------------------------------------------------
template<int KSTEPS, int NFRAGS, bool A_F32K16, bool RELU, bool ADD_P, bool HASBIAS>
__global__ __launch_bounds__(256) void gemm_mfma(
    const void* __restrict__ Xv, int lda, int xk_ystride,
    const unsigned short* __restrict__ Wf, int wf_ystride,
    const float* __restrict__ bias, const float* __restrict__ Pp,
    unsigned short* __restrict__ Y, int ldy)
{
    const int y    = blockIdx.y;
    const int row0 = blockIdx.x * 64;
    const int tid  = threadIdx.x;
    const int w = tid >> 6, l = tid & 63;
    const int wm = w >> 1, wn = w & 1;
    const int lm = l & 15, lk = l >> 4;
    const int wrow  = row0 + wm * 32;
    const int gcol0 = y * (NFRAGS * 32) + wn * (NFRAGS * 16);
    const unsigned short* wfp = Wf + (size_t)y * wf_ystride + (size_t)l * 8;

    f32x4 acc[2][NFRAGS];
#pragma unroll
    for (int rf = 0; rf < 2; rf++)
#pragma unroll
        for (int nf = 0; nf < NFRAGS; nf++)
            acc[rf][nf] = (f32x4){0.f, 0.f, 0.f, 0.f};

#pragma unroll
    for (int ks = 0; ks < KSTEPS; ks++) {
        bf16x8 a[2];
        if (A_F32K16) {
            const float* X = (const float*)Xv;
#pragma unroll
            for (int rf = 0; rf < 2; rf++) {
                bf16x8 t = {0, 0, 0, 0, 0, 0, 0, 0};
                if (lk < 2) {
                    const float* p = X + (size_t)(wrow + rf * 16 + lm) * lda + lk * 8;
                    const float4 v0 = *reinterpret_cast<const float4*>(p);
                    const float4 v1 = *reinterpret_cast<const float4*>(p + 4);
                    t[0] = (short)f2bfu(v0.x); t[1] = (short)f2bfu(v0.y);
                    t[2] = (short)f2bfu(v0.z); t[3] = (short)f2bfu(v0.w);
                    t[4] = (short)f2bfu(v1.x); t[5] = (short)f2bfu(v1.y);
                    t[6] = (short)f2bfu(v1.z); t[7] = (short)f2bfu(v1.w);
                }
                a[rf] = t;
            }
        } else {
            const unsigned short* X = (const unsigned short*)Xv;
            const unsigned short* p = X + (size_t)(wrow + lm) * lda +
                                      (size_t)y * xk_ystride + lk * 8 + ks * 32;
            a[0] = *reinterpret_cast<const bf16x8*>(p);
            a[1] = *reinterpret_cast<const bf16x8*>(p + (size_t)16 * lda);
        }
#pragma unroll
        for (int nf = 0; nf < NFRAGS; nf++) {
            const bf16x8 b = *reinterpret_cast<const bf16x8*>(
                wfp + (size_t)(ks * (2 * NFRAGS) + wn * NFRAGS + nf) * 512);
            acc[0][nf] = __builtin_amdgcn_mfma_f32_16x16x32_bf16(a[0], b, acc[0][nf], 0, 0, 0);
            acc[1][nf] = __builtin_amdgcn_mfma_f32_16x16x32_bf16(a[1], b, acc[1][nf], 0, 0, 0);
        }
    }

#pragma unroll
    for (int rf = 0; rf < 2; rf++) {
        const int r0 = wrow + rf * 16 + lk * 4;
        const int tt = (r0 >> 7) & 255;
#pragma unroll
        for (int nf = 0; nf < NFRAGS; nf++) {
            const int gc = gcol0 + nf * 16 + lm;
            float add = 0.f;
            if (HASBIAS) add = bias[gc];
            if (ADD_P) { if (y == 1 && tt < 255) add += Pp[(size_t)tt * 288 + (gc - 288)]; }
#pragma unroll
            for (int reg = 0; reg < 4; reg++) {
                float v = acc[rf][nf][reg] + add;
                if (RELU) v = fmaxf(v, 0.f);
                Y[(size_t)(r0 + reg) * ldy + gc] = f2bfu(v);
            }
        }
    }
}

// ---------------------------------------------------------------------------
// Final: out[bt,e,c] = relu(SR[s_row][0:288] + SR[r_row][288:576]) @ Wc2 + bc2
// (P, bc1 folded into R' half.) One wave per 16-edge tile, 9 MFMA per tile.
// ---------------------------------------------------------------------------
__global__ __launch_bounds__(256) void final_mfma(
    const unsigned short* __restrict__ SR,
    const unsigned short* __restrict__ wc2f, const float* __restrict__ bc2,
    const int* __restrict__ se, const int* __restrict__ re,
    float* __restrict__ out)
{
    const int bid  = blockIdx.x;                 // 2040 = 8 * 255
    const int task = (bid & 7) * 255 + (bid >> 3);
    const int bt = task >> 2, tg = task & 3;
    const int b = bt / 255, t = bt % 255;
    const int tid = threadIdx.x, w = tid >> 6, l = tid & 63;
    const int lm = l & 15, lk = l >> 4;

    bf16x8 bfrag[9];
#pragma unroll
    for (int ks = 0; ks < 9; ks++)
        bfrag[ks] = *reinterpret_cast<const bf16x8*>(wc2f + (ks * 64 + l) * 8);

    const float bias = (lm < 5) ? bc2[lm] : 0.f;

    const unsigned short* Sb = SR + (size_t)((b * 256 + t + 1) * 128) * 576 + lk * 8;
    const unsigned short* Rb = SR + (size_t)((b * 256 + t) * 128) * 576 + 288 + lk * 8;

    for (int it = 0; it < 4; it++) {
        const int e0 = (tg * 16 + w * 4 + it) * 16;
        const unsigned short* Srow = Sb + (size_t)se[e0 + lm] * 576;
        const unsigned short* Rrow = Rb + (size_t)re[e0 + lm] * 576;
        f32x4 acc = {0.f, 0.f, 0.f, 0.f};
#pragma unroll
        for (int ks = 0; ks < 9; ks++) {
            const bf16x8 s8 = *reinterpret_cast<const bf16x8*>(Srow + ks * 32);
            const bf16x8 r8 = *reinterpret_cast<const bf16x8*>(Rrow + ks * 32);
            bf16x8 h;
#pragma unroll
            for (int j = 0; j < 8; j++) {
                union { unsigned u; float f; } cs, cr;
                cs.u = ((unsigned)(unsigned short)s8[j]) << 16;
                cr.u = ((unsigned)(unsigned short)r8[j]) << 16;
                h[j] = (short)f2bfu(fmaxf(cs.f + cr.f, 0.f));
            }
            acc = __builtin_amdgcn_mfma_f32_16x16x32_bf16(h, bfrag[ks], acc, 0, 0, 0);
        }
        if (lm < 5) {
            float* op = out + ((size_t)bt * 1024 + e0 + lk * 4) * 5 + lm;
            op[0]  = acc[0] + bias;
            op[5]  = acc[1] + bias;
            op[10] = acc[2] + bias;
            op[15] = acc[3] + bias;
        }
    }
}

// ---------------------------------------------------------------------------
extern "C" void kernel_launch(void* const* d_in, const int* in_sizes, int n_in,
                              void* d_out, int out_size, void* d_ws, size_t ws_size,
                              hipStream_t stream)
{
    const float* spikes = (const float*)d_in[0];
    const float* W_emb  = (const float*)d_in[1];
    const float* b_emb  = (const float*)d_in[2];
    const float* Ws1    = (const float*)d_in[3];
    const float* bs1    = (const float*)d_in[4];
    const float* Ws2    = (const float*)d_in[5];
    const float* bs2    = (const float*)d_in[6];
    const float* Wr1    = (const float*)d_in[7];
    const float* br1    = (const float*)d_in[8];
    const float* Wr2    = (const float*)d_in[9];
    const float* br2    = (const float*)d_in[10];
    const float* Wc1    = (const float*)d_in[11];
    const float* bc1    = (const float*)d_in[12];
    const float* Wc2    = (const float*)d_in[13];
    const float* bc2    = (const float*)d_in[14];
    const int*   se     = (const int*)d_in[15];
    const int*   re     = (const int*)d_in[16];

    float* out = (float*)d_out;
    float* ws  = (float*)d_ws;

    // workspace layout (float offsets, all 16B-aligned):
    float*          P     = ws;                                   // 73,440 f
    float*          bias1 = ws + 73440;                           // 256 f
    float*          bias2 = ws + 73696;                           // 256 f
    unsigned short* wg1f  = (unsigned short*)(ws + 73952);        // 8,192 u16
    unsigned short* wg2f  = (unsigned short*)(ws + 78048);        // 32,768 u16
    unsigned short* wg3f  = (unsigned short*)(ws + 94432);        // 73,728 u16
    unsigned short* wc2f  = (unsigned short*)(ws + 131296);       // 4,608 u16
    unsigned short* h1    = (unsigned short*)(ws + 133600);       // 65536*256 u16
    unsigned short* h2    = (unsigned short*)(ws + 8522208);      // 65536*256 u16
    unsigned short* SR    = (unsigned short*)(ws + 16910816);     // 65536*576 u16

    const dim3 blk(256);

    prep_kernel<<<756, blk, 0, stream>>>(
        W_emb, b_emb, Ws1, bs1, Wr1, br1, Ws2, bs2, Wr2, br2, Wc1, bc1, Wc2,
        P, bias1, bias2, wg1f, wg2f, wg3f, wc2f);

    // h1 = relu(spikes @ [W_emb@Ws1 | W_emb@Wr1] + bias1)   (K=16, N=256)
    gemm_mfma<1, 4, true, true, false, true><<<dim3(1024, 2), blk, 0, stream>>>(
        spikes, 16, 0, wg1f, 4096, bias1, nullptr, h1, 256);
    // h2 = relu(h1 @ diag(Ws2, Wr2) + bias2)                (K=128, N=256)
    gemm_mfma<4, 4, false, true, false, true><<<dim3(1024, 2), blk, 0, stream>>>(
        h1, 256, 128, wg2f, 16384, bias2, nullptr, h2, 256);
    // SR = h2 @ diag(Wc1a, Wc1b) + [0 | P]                  (K=128, N=576)
    gemm_mfma<4, 9, false, false, true, false><<<dim3(1024, 2), blk, 0, stream>>>(
        h2, 256, 128, wg3f, 36864, nullptr, P, SR, 576);
    // gather + relu + head
    final_mfma<<<2040, blk, 0, stream>>>(SR, wc2f, bc2, se, re, out);
}

// Round 4
// 128.907 us; speedup vs baseline: 4.0852x; 1.2036x over previous
//
#include <hip/hip_runtime.h>
#include <cstdint>
#include <cstddef>

typedef __attribute__((ext_vector_type(8))) short bf16x8;
typedef __attribute__((ext_vector_type(4))) float f32x4;

__device__ inline unsigned short f2bfu(float f) {  // RNE pack (finite values)
    union { float f; unsigned u; } c; c.f = f;
    unsigned r = c.u + 0x7FFFu + ((c.u >> 16) & 1u);
    return (unsigned short)(r >> 16);
}

// ---------------------------------------------------------------------------
// One-shot prep: P (PE@Wc1 + bc1), folded first-layer weights/biases, and all
// weights converted to bf16 in MFMA B-fragment order:
//   frag[f*512 + l*8 + j] = W[ks*32 + (l>>4)*8 + j][nf*16 + (l&15)]
// ---------------------------------------------------------------------------
__global__ void prep_kernel(
    const float* __restrict__ W_emb, const float* __restrict__ b_emb,
    const float* __restrict__ Ws1, const float* __restrict__ bs1,
    const float* __restrict__ Wr1, const float* __restrict__ br1,
    const float* __restrict__ Ws2, const float* __restrict__ bs2,
    const float* __restrict__ Wr2, const float* __restrict__ br2,
    const float* __restrict__ Wc1, const float* __restrict__ bc1,
    const float* __restrict__ Wc2,
    float* __restrict__ P, float* __restrict__ bias1, float* __restrict__ bias2,
    unsigned short* __restrict__ wg1f, unsigned short* __restrict__ wg2f,
    unsigned short* __restrict__ wg3f, unsigned short* __restrict__ wc2f)
{
    int id = blockIdx.x * 256 + threadIdx.x;

    if (id < 73440) {   // P[t,h] = pe[t+1]@Wc1[128:144] + pe[t]@Wc1[272:288] + bc1
        const int t = id / 288, ho = id % 288;
        float acc = bc1[ho];
#pragma unroll
        for (int i = 0; i < 8; i++) {
            const float div = expf(-1.1512925464970229f * (float)i);
            const float a1 = (float)(t + 1) * div;
            const float a0 = (float)t * div;
            acc += sinf(a1) * Wc1[(size_t)(128 + 2 * i) * 288 + ho];
            acc += cosf(a1) * Wc1[(size_t)(129 + 2 * i) * 288 + ho];
            acc += sinf(a0) * Wc1[(size_t)(272 + 2 * i) * 288 + ho];
            acc += cosf(a0) * Wc1[(size_t)(273 + 2 * i) * 288 + ho];
        }
        P[id] = acc;
        return;
    }
    id -= 73440;

    if (id < 8192) {    // wg1f: [W_emb@Ws1 | W_emb@Wr1], K padded 16->32
        const int y = id >> 12, r = id & 4095;
        const int f = r >> 9, l = (r >> 3) & 63, j = r & 7;
        const int k = ((l >> 4) << 3) + j;          // 0..31
        const int n = f * 16 + (l & 15);
        float v = 0.f;
        if (k < 16) {
            const float* Wx = y ? Wr1 : Ws1;
            for (int d = 0; d < 128; d++) v += W_emb[k * 128 + d] * Wx[d * 128 + n];
        }
        wg1f[id] = f2bfu(v);
        return;
    }
    id -= 8192;

    if (id < 256) {     // bias1 = [bs1 + b_emb@Ws1 | br1 + b_emb@Wr1]
        const int y = id >> 7, c = id & 127;
        const float* Wx = y ? Wr1 : Ws1;
        float v = (y ? br1 : bs1)[c];
        for (int d = 0; d < 128; d++) v += b_emb[d] * Wx[d * 128 + c];
        bias1[id] = v;
        return;
    }
    id -= 256;

    if (id < 32768) {   // wg2f: [Ws2 | Wr2] fragments
        const int y = id >> 14, r = id & 16383;
        const int f = r >> 9, l = (r >> 3) & 63, j = r & 7;
        const int ks = f >> 3, nf = f & 7;
        const int k = ks * 32 + ((l >> 4) << 3) + j;
        const int n = nf * 16 + (l & 15);
        wg2f[id] = f2bfu((y ? Wr2 : Ws2)[(size_t)k * 128 + n]);
        return;
    }
    id -= 32768;

    if (id < 256) {     // bias2 = [bs2 | br2]
        bias2[id] = (id < 128) ? bs2[id] : br2[id - 128];
        return;
    }
    id -= 256;

    if (id < 73728) {   // wg3f: [Wc1[0:128,:] | Wc1[144:272,:]] fragments
        const int y = id / 36864, r = id % 36864;
        const int f = r >> 9, l = (r >> 3) & 63, j = r & 7;
        const int ks = f / 18, nf = f % 18;
        const int k = ks * 32 + ((l >> 4) << 3) + j;
        const int n = nf * 16 + (l & 15);
        wg3f[id] = f2bfu(Wc1[(size_t)(y * 144 + k) * 288 + n]);
        return;
    }
    id -= 73728;

    if (id < 4608) {    // wc2f: head weight fragments (288x5 padded to 16 cols)
        const int j = id & 7, l = (id >> 3) & 63, ks = id >> 9;
        const int k = ks * 32 + ((l >> 4) << 3) + j;
        const int c = l & 15;
        wc2f[id] = (c < 5) ? f2bfu(Wc2[(size_t)k * 5 + c]) : (unsigned short)0;
    }
}

// ---------------------------------------------------------------------------
// bf16 MFMA GEMM, no LDS. Block = 64 rows x (NFRAGS*32) cols, 4 waves (2x2).
// blockIdx.y selects weight block (block-diagonal fusion) and A k-offset.
// A_F32K16: A is fp32 with K=16 (padded to 32 with zeros in-register).
// ADD_P: y==1 half adds P[t*288 + (gc-288)] (t = (row>>7)&255, skip t==255).
// ---------------------------------------------------------------------------
template<int KSTEPS, int NFRAGS, bool A_F32K16, bool RELU, bool ADD_P, bool HASBIAS>
__global__ __launch_bounds__(256) void gemm_mfma(
    const void* __restrict__ Xv, int lda, int xk_ystride,
    const unsigned short* __restrict__ Wf, int wf_ystride,
    const float* __restrict__ bias, const float* __restrict__ Pp,
    unsigned short* __restrict__ Y, int ldy)
{
    const int y    = blockIdx.y;
    const int row0 = blockIdx.x * 64;
    const int tid  = threadIdx.x;
    const int w = tid >> 6, l = tid & 63;
    const int wm = w >> 1, wn = w & 1;
    const int lm = l & 15, lk = l >> 4;
    const int wrow  = row0 + wm * 32;
    const int gcol0 = y * (NFRAGS * 32) + wn * (NFRAGS * 16);
    const unsigned short* wfp = Wf + (size_t)y * wf_ystride + (size_t)l * 8;

    f32x4 acc[2][NFRAGS];
#pragma unroll
    for (int rf = 0; rf < 2; rf++)
#pragma unroll
        for (int nf = 0; nf < NFRAGS; nf++)
            acc[rf][nf] = (f32x4){0.f, 0.f, 0.f, 0.f};

#pragma unroll
    for (int ks = 0; ks < KSTEPS; ks++) {
        bf16x8 a[2];
        if (A_F32K16) {
            const float* X = (const float*)Xv;
#pragma unroll
            for (int rf = 0; rf < 2; rf++) {
                bf16x8 t = {0, 0, 0, 0, 0, 0, 0, 0};
                if (lk < 2) {
                    const float* p = X + (size_t)(wrow + rf * 16 + lm) * lda + lk * 8;
                    const float4 v0 = *reinterpret_cast<const float4*>(p);
                    const float4 v1 = *reinterpret_cast<const float4*>(p + 4);
                    t[0] = (short)f2bfu(v0.x); t[1] = (short)f2bfu(v0.y);
                    t[2] = (short)f2bfu(v0.z); t[3] = (short)f2bfu(v0.w);
                    t[4] = (short)f2bfu(v1.x); t[5] = (short)f2bfu(v1.y);
                    t[6] = (short)f2bfu(v1.z); t[7] = (short)f2bfu(v1.w);
                }
                a[rf] = t;
            }
        } else {
            const unsigned short* X = (const unsigned short*)Xv;
            const unsigned short* p = X + (size_t)(wrow + lm) * lda +
                                      (size_t)y * xk_ystride + lk * 8 + ks * 32;
            a[0] = *reinterpret_cast<const bf16x8*>(p);
            a[1] = *reinterpret_cast<const bf16x8*>(p + (size_t)16 * lda);
        }
#pragma unroll
        for (int nf = 0; nf < NFRAGS; nf++) {
            const bf16x8 b = *reinterpret_cast<const bf16x8*>(
                wfp + (size_t)(ks * (2 * NFRAGS) + wn * NFRAGS + nf) * 512);
            acc[0][nf] = __builtin_amdgcn_mfma_f32_16x16x32_bf16(a[0], b, acc[0][nf], 0, 0, 0);
            acc[1][nf] = __builtin_amdgcn_mfma_f32_16x16x32_bf16(a[1], b, acc[1][nf], 0, 0, 0);
        }
    }

#pragma unroll
    for (int rf = 0; rf < 2; rf++) {
        const int r0 = wrow + rf * 16 + lk * 4;
        const int tt = (r0 >> 7) & 255;
#pragma unroll
        for (int nf = 0; nf < NFRAGS; nf++) {
            const int gc = gcol0 + nf * 16 + lm;
            float add = 0.f;
            if (HASBIAS) add = bias[gc];
            if (ADD_P) { if (y == 1 && tt < 255) add += Pp[(size_t)tt * 288 + (gc - 288)]; }
#pragma unroll
            for (int reg = 0; reg < 4; reg++) {
                float v = acc[rf][nf][reg] + add;
                if (RELU) v = fmaxf(v, 0.f);
                Y[(size_t)(r0 + reg) * ldy + gc] = f2bfu(v);
            }
        }
    }
}

// ---------------------------------------------------------------------------
// Final: one block per (b,t) slice. Stage the slice's S rows (128x288 bf16)
// and R' rows (128x288 bf16) into LDS once, then all 64 edge tiles read LDS.
// LDS layout per matrix: [36 chunks][128 rows][8 bf16], chunk stride padded
// to 2064 B (rows land in distinct bank groups). 1024 threads = 16 waves,
// each wave does 4 tiles of 16 edges, 9 MFMA 16x16x32 per tile.
// ---------------------------------------------------------------------------
#define CH_STRIDE 2064
#define R_BASE    74304      // 36 * 2064
#define LDS_BYTES 148608     // 2 * 74304

__global__ __launch_bounds__(1024) void final_fused(
    const unsigned short* __restrict__ SR,
    const unsigned short* __restrict__ wc2f, const float* __restrict__ bc2,
    const int* __restrict__ se, const int* __restrict__ re,
    float* __restrict__ out)
{
    extern __shared__ unsigned char lds[];
    const int slice = blockIdx.x;            // 0..509
    const int b = slice / 255, t = slice % 255;
    const int tid = threadIdx.x;

    // ---- stage S (chunks 0..4607) and R' (4608..9215) into LDS ----
    const size_t srow0 = (size_t)((b * 256 + t + 1) * 128) * 576;
    const size_t rrow0 = (size_t)((b * 256 + t) * 128) * 576 + 288;
#pragma unroll
    for (int c = tid; c < 9216; c += 1024) {
        const int m   = (c >= 4608);
        const int cc  = m ? c - 4608 : c;
        const int row = cc / 36, ch = cc % 36;
        const bf16x8 v = *reinterpret_cast<const bf16x8*>(
            SR + (m ? rrow0 : srow0) + (size_t)row * 576 + ch * 8);
        *reinterpret_cast<bf16x8*>(lds + m * R_BASE + ch * CH_STRIDE + row * 16) = v;
    }

    const int w = tid >> 6, l = tid & 63;
    const int lm = l & 15, lk = l >> 4;

    bf16x8 bfrag[9];
#pragma unroll
    for (int ks = 0; ks < 9; ks++)
        bfrag[ks] = *reinterpret_cast<const bf16x8*>(wc2f + (ks * 64 + l) * 8);
    const float bias = (lm < 5) ? bc2[lm] : 0.f;

    __syncthreads();

    // ---- 64 tiles of 16 edges; wave w owns tiles 4w..4w+3 ----
    for (int it = 0; it < 4; it++) {
        const int e0  = (w * 4 + it) * 16;
        const int srw = se[e0 + lm];
        const int rrw = re[e0 + lm];
        f32x4 acc = {0.f, 0.f, 0.f, 0.f};
#pragma unroll
        for (int ks = 0; ks < 9; ks++) {
            const int ch = ks * 4 + lk;
            const bf16x8 s8 = *reinterpret_cast<const bf16x8*>(
                lds + ch * CH_STRIDE + srw * 16);
            const bf16x8 r8 = *reinterpret_cast<const bf16x8*>(
                lds + R_BASE + ch * CH_STRIDE + rrw * 16);
            bf16x8 h;
#pragma unroll
            for (int j = 0; j < 8; j++) {
                union { unsigned u; float f; } cs, cr;
                cs.u = ((unsigned)(unsigned short)s8[j]) << 16;
                cr.u = ((unsigned)(unsigned short)r8[j]) << 16;
                h[j] = (short)f2bfu(fmaxf(cs.f + cr.f, 0.f));
            }
            acc = __builtin_amdgcn_mfma_f32_16x16x32_bf16(h, bfrag[ks], acc, 0, 0, 0);
        }
        if (lm < 5) {
            float* op = out + ((size_t)slice * 1024 + e0 + lk * 4) * 5 + lm;
            op[0]  = acc[0] + bias;
            op[5]  = acc[1] + bias;
            op[10] = acc[2] + bias;
            op[15] = acc[3] + bias;
        }
    }
}

// ---------------------------------------------------------------------------
extern "C" void kernel_launch(void* const* d_in, const int* in_sizes, int n_in,
                              void* d_out, int out_size, void* d_ws, size_t ws_size,
                              hipStream_t stream)
{
    const float* spikes = (const float*)d_in[0];
    const float* W_emb  = (const float*)d_in[1];
    const float* b_emb  = (const float*)d_in[2];
    const float* Ws1    = (const float*)d_in[3];
    const float* bs1    = (const float*)d_in[4];
    const float* Ws2    = (const float*)d_in[5];
    const float* bs2    = (const float*)d_in[6];
    const float* Wr1    = (const float*)d_in[7];
    const float* br1    = (const float*)d_in[8];
    const float* Wr2    = (const float*)d_in[9];
    const float* br2    = (const float*)d_in[10];
    const float* Wc1    = (const float*)d_in[11];
    const float* bc1    = (const float*)d_in[12];
    const float* Wc2    = (const float*)d_in[13];
    const float* bc2    = (const float*)d_in[14];
    const int*   se     = (const int*)d_in[15];
    const int*   re     = (const int*)d_in[16];

    float* out = (float*)d_out;
    float* ws  = (float*)d_ws;

    // workspace layout (float offsets, all 16B-aligned):
    float*          P     = ws;                                   // 73,440 f
    float*          bias1 = ws + 73440;                           // 256 f
    float*          bias2 = ws + 73696;                           // 256 f
    unsigned short* wg1f  = (unsigned short*)(ws + 73952);        // 8,192 u16
    unsigned short* wg2f  = (unsigned short*)(ws + 78048);        // 32,768 u16
    unsigned short* wg3f  = (unsigned short*)(ws + 94432);        // 73,728 u16
    unsigned short* wc2f  = (unsigned short*)(ws + 131296);       // 4,608 u16
    unsigned short* h1    = (unsigned short*)(ws + 133600);       // 65536*256 u16
    unsigned short* h2    = (unsigned short*)(ws + 8522208);      // 65536*256 u16
    unsigned short* SR    = (unsigned short*)(ws + 16910816);     // 65536*576 u16

    const dim3 blk(256);

    hipFuncSetAttribute(reinterpret_cast<const void*>(final_fused),
                        hipFuncAttributeMaxDynamicSharedMemorySize, LDS_BYTES);

    prep_kernel<<<756, blk, 0, stream>>>(
        W_emb, b_emb, Ws1, bs1, Wr1, br1, Ws2, bs2, Wr2, br2, Wc1, bc1, Wc2,
        P, bias1, bias2, wg1f, wg2f, wg3f, wc2f);

    // h1 = relu(spikes @ [W_emb@Ws1 | W_emb@Wr1] + bias1)  (K=16, N=256, 1 pass)
    gemm_mfma<1, 8, true, true, false, true><<<dim3(1024, 1), blk, 0, stream>>>(
        spikes, 16, 0, wg1f, 0, bias1, nullptr, h1, 256);
    // h2 = relu(h1 @ diag(Ws2, Wr2) + bias2)               (K=128, N=256)
    gemm_mfma<4, 4, false, true, false, true><<<dim3(1024, 2), blk, 0, stream>>>(
        h1, 256, 128, wg2f, 16384, bias2, nullptr, h2, 256);
    // SR = h2 @ diag(Wc1a, Wc1b) + [0 | P]                 (K=128, N=576)
    gemm_mfma<4, 9, false, false, true, false><<<dim3(1024, 2), blk, 0, stream>>>(
        h2, 256, 128, wg3f, 36864, nullptr, P, SR, 576);
    // gather + relu + head, LDS-staged per slice
    final_fused<<<510, dim3(1024), LDS_BYTES, stream>>>(SR, wc2f, bc2, se, re, out);
}

// Round 6
// 94.527 us; speedup vs baseline: 5.5710x; 1.3637x over previous
//
#include <hip/hip_runtime.h>
#include <hip/hip_bf16.h>
#include <cstdint>
#include <cstddef>

typedef __attribute__((ext_vector_type(8))) short bf16x8;
typedef __attribute__((ext_vector_type(4))) float f32x4;
typedef __attribute__((ext_vector_type(4))) unsigned u32x4;

__device__ inline unsigned short f2bf(float f) {   // RNE
    __hip_bfloat16 h = __float2bfloat16(f);
    return __builtin_bit_cast(unsigned short, h);
}

// ---------------------------------------------------------------------------
// One-shot prep: P (PE@Wc1 + bc1), folded first-layer weights/biases, and all
// weights converted to bf16 in MFMA B-fragment order:
//   frag[f*512 + l*8 + j] = W[ks*32 + (l>>4)*8 + j][nf*16 + (l&15)]
// ---------------------------------------------------------------------------
__global__ void prep_kernel(
    const float* __restrict__ W_emb, const float* __restrict__ b_emb,
    const float* __restrict__ Ws1, const float* __restrict__ bs1,
    const float* __restrict__ Wr1, const float* __restrict__ br1,
    const float* __restrict__ Ws2, const float* __restrict__ bs2,
    const float* __restrict__ Wr2, const float* __restrict__ br2,
    const float* __restrict__ Wc1, const float* __restrict__ bc1,
    const float* __restrict__ Wc2,
    float* __restrict__ P, float* __restrict__ bias1, float* __restrict__ bias2,
    unsigned short* __restrict__ wg1f, unsigned short* __restrict__ wg2f,
    unsigned short* __restrict__ wg3f, unsigned short* __restrict__ wc2f)
{
    int id = blockIdx.x * 256 + threadIdx.x;

    if (id < 73440) {   // P[t,h] = pe[t+1]@Wc1[128:144] + pe[t]@Wc1[272:288] + bc1
        const int t = id / 288, ho = id % 288;
        float acc = bc1[ho];
#pragma unroll
        for (int i = 0; i < 8; i++) {
            const float div = expf(-1.1512925464970229f * (float)i);
            const float a1 = (float)(t + 1) * div;
            const float a0 = (float)t * div;
            acc += sinf(a1) * Wc1[(size_t)(128 + 2 * i) * 288 + ho];
            acc += cosf(a1) * Wc1[(size_t)(129 + 2 * i) * 288 + ho];
            acc += sinf(a0) * Wc1[(size_t)(272 + 2 * i) * 288 + ho];
            acc += cosf(a0) * Wc1[(size_t)(273 + 2 * i) * 288 + ho];
        }
        P[id] = acc;
        return;
    }
    id -= 73440;

    if (id < 8192) {    // wg1f: [W_emb@Ws1 | W_emb@Wr1], K padded 16->32
        const int y = id >> 12, r = id & 4095;
        const int f = r >> 9, l = (r >> 3) & 63, j = r & 7;
        const int k = ((l >> 4) << 3) + j;          // 0..31
        const int n = f * 16 + (l & 15);
        float v = 0.f;
        if (k < 16) {
            const float* Wx = y ? Wr1 : Ws1;
            for (int d = 0; d < 128; d++) v += W_emb[k * 128 + d] * Wx[d * 128 + n];
        }
        wg1f[id] = f2bf(v);
        return;
    }
    id -= 8192;

    if (id < 256) {     // bias1 = [bs1 + b_emb@Ws1 | br1 + b_emb@Wr1]
        const int y = id >> 7, c = id & 127;
        const float* Wx = y ? Wr1 : Ws1;
        float v = (y ? br1 : bs1)[c];
        for (int d = 0; d < 128; d++) v += b_emb[d] * Wx[d * 128 + c];
        bias1[id] = v;
        return;
    }
    id -= 256;

    if (id < 32768) {   // wg2f: [Ws2 | Wr2] fragments
        const int y = id >> 14, r = id & 16383;
        const int f = r >> 9, l = (r >> 3) & 63, j = r & 7;
        const int ks = f >> 3, nf = f & 7;
        const int k = ks * 32 + ((l >> 4) << 3) + j;
        const int n = nf * 16 + (l & 15);
        wg2f[id] = f2bf((y ? Wr2 : Ws2)[(size_t)k * 128 + n]);
        return;
    }
    id -= 32768;

    if (id < 256) {     // bias2 = [bs2 | br2]
        bias2[id] = (id < 128) ? bs2[id] : br2[id - 128];
        return;
    }
    id -= 256;

    if (id < 73728) {   // wg3f: [Wc1[0:128,:] | Wc1[144:272,:]] fragments
        const int y = id / 36864, r = id % 36864;
        const int f = r >> 9, l = (r >> 3) & 63, j = r & 7;
        const int ks = f / 18, nf = f % 18;
        const int k = ks * 32 + ((l >> 4) << 3) + j;
        const int n = nf * 16 + (l & 15);
        wg3f[id] = f2bf(Wc1[(size_t)(y * 144 + k) * 288 + n]);
        return;
    }
    id -= 73728;

    if (id < 4608) {    // wc2f: head weight fragments (288x5 padded to 16 cols)
        const int j = id & 7, l = (id >> 3) & 63, ks = id >> 9;
        const int k = ks * 32 + ((l >> 4) << 3) + j;
        const int c = l & 15;
        wc2f[id] = (c < 5) ? f2bf(Wc2[(size_t)k * 5 + c]) : (unsigned short)0;
    }
}

// ---------------------------------------------------------------------------
// Kernel A: h2 = relu( relu(spikes @ wg1 + bias1) @ diag(Ws2,Wr2) + bias2 )
// 64 rows/block, 4 waves (2 row x 2 col). h1 lives in LDS (stride 528 B:
// 132 dwords/row -> 4-bank rotation per row -> uniform bank spread).
// ---------------------------------------------------------------------------
#define H1S 264   // shorts per h1 LDS row

__global__ __launch_bounds__(256) void fused12(
    const float* __restrict__ spikes,
    const unsigned short* __restrict__ wg1f, const float* __restrict__ bias1,
    const unsigned short* __restrict__ wg2f, const float* __restrict__ bias2,
    unsigned short* __restrict__ h2)
{
    __shared__ unsigned short h1l[64 * H1S];     // 33,792 B
    const int row0 = blockIdx.x * 64;
    const int tid = threadIdx.x;
    const int w = tid >> 6, l = tid & 63;
    const int wm = w >> 1, wn = w & 1;
    const int lm = l & 15, lk = l >> 4;
    const int wrow = wm * 32;                    // local row base

    // ---- stage 0: h1 = relu(spikes @ wg1 + bias1), K=16 padded to 32 ----
    bf16x8 a0[2];
#pragma unroll
    for (int rf = 0; rf < 2; rf++) {
        bf16x8 tv = {0, 0, 0, 0, 0, 0, 0, 0};
        if (lk < 2) {
            const float* p = spikes + (size_t)(row0 + wrow + rf * 16 + lm) * 16 + lk * 8;
            const float4 v0 = *reinterpret_cast<const float4*>(p);
            const float4 v1 = *reinterpret_cast<const float4*>(p + 4);
            tv[0] = (short)f2bf(v0.x); tv[1] = (short)f2bf(v0.y);
            tv[2] = (short)f2bf(v0.z); tv[3] = (short)f2bf(v0.w);
            tv[4] = (short)f2bf(v1.x); tv[5] = (short)f2bf(v1.y);
            tv[6] = (short)f2bf(v1.z); tv[7] = (short)f2bf(v1.w);
        }
        a0[rf] = tv;
    }
    f32x4 acc[2][8];
#pragma unroll
    for (int rf = 0; rf < 2; rf++)
#pragma unroll
        for (int nf = 0; nf < 8; nf++) acc[rf][nf] = (f32x4){0.f, 0.f, 0.f, 0.f};

#pragma unroll
    for (int nf = 0; nf < 8; nf++) {
        const bf16x8 bfr = *reinterpret_cast<const bf16x8*>(
            wg1f + (size_t)(wn * 8 + nf) * 512 + l * 8);
        acc[0][nf] = __builtin_amdgcn_mfma_f32_16x16x32_bf16(a0[0], bfr, acc[0][nf], 0, 0, 0);
        acc[1][nf] = __builtin_amdgcn_mfma_f32_16x16x32_bf16(a0[1], bfr, acc[1][nf], 0, 0, 0);
    }
#pragma unroll
    for (int rf = 0; rf < 2; rf++)
#pragma unroll
        for (int nf = 0; nf < 8; nf++) {
            const int gc = wn * 128 + nf * 16 + lm;
            const float add = bias1[gc];
#pragma unroll
            for (int reg = 0; reg < 4; reg++) {
                const int r = wrow + rf * 16 + lk * 4 + reg;
                h1l[r * H1S + gc] = f2bf(fmaxf(acc[rf][nf][reg] + add, 0.f));
            }
        }
    __syncthreads();

    // ---- stage 1: h2 = relu(h1 @ diag(Ws2,Wr2) + bias2), K=128 per half ----
#pragma unroll
    for (int rf = 0; rf < 2; rf++)
#pragma unroll
        for (int nf = 0; nf < 8; nf++) acc[rf][nf] = (f32x4){0.f, 0.f, 0.f, 0.f};

#pragma unroll
    for (int ks = 0; ks < 4; ks++) {
        bf16x8 a[2];
        a[0] = *reinterpret_cast<const bf16x8*>(
            &h1l[(wrow + lm) * H1S + wn * 128 + ks * 32 + lk * 8]);
        a[1] = *reinterpret_cast<const bf16x8*>(
            &h1l[(wrow + 16 + lm) * H1S + wn * 128 + ks * 32 + lk * 8]);
#pragma unroll
        for (int nf = 0; nf < 8; nf++) {
            const bf16x8 bfr = *reinterpret_cast<const bf16x8*>(
                wg2f + (size_t)wn * 16384 + (size_t)(ks * 8 + nf) * 512 + l * 8);
            acc[0][nf] = __builtin_amdgcn_mfma_f32_16x16x32_bf16(a[0], bfr, acc[0][nf], 0, 0, 0);
            acc[1][nf] = __builtin_amdgcn_mfma_f32_16x16x32_bf16(a[1], bfr, acc[1][nf], 0, 0, 0);
        }
    }
#pragma unroll
    for (int rf = 0; rf < 2; rf++)
#pragma unroll
        for (int nf = 0; nf < 8; nf++) {
            const int gc = wn * 128 + nf * 16 + lm;
            const float add = bias2[gc];
#pragma unroll
            for (int reg = 0; reg < 4; reg++) {
                const size_t r = (size_t)(row0 + wrow + rf * 16 + lk * 4 + reg);
                h2[r * 256 + gc] = f2bf(fmaxf(acc[rf][nf][reg] + add, 0.f));
            }
        }
}

// ---------------------------------------------------------------------------
// Kernel B: per (b,t) slice.
// Phase 1 (2 passes x 16 waves): S = h2(t+1)@Wc1a, R' = h2(t)@Wc1b + P(t),
// written straight into LDS as bf16 (never touches HBM).
// LDS layout per matrix: [144 col-pair dwords][128 rows], dword stride
// QCS=516 B (129 dwords, odd -> gathered rows spread across all 32 banks).
// Phase 2: head. Per 16-edge tile: gather rows, h = relu(S+R) via
// v_cvt_pk_bf16_f32 (inline asm), 9 MFMA 16x16x32 -> out.
// ---------------------------------------------------------------------------
#define QCS      516
#define SR_HALF  74304      // 144 * 516
#define LDS_B    148608     // 2 * SR_HALF

__global__ __launch_bounds__(1024) void final3(
    const unsigned short* __restrict__ h2,
    const unsigned short* __restrict__ wg3f, const float* __restrict__ Pt,
    const unsigned short* __restrict__ wc2f, const float* __restrict__ bc2,
    const int* __restrict__ se, const int* __restrict__ re,
    float* __restrict__ out)
{
    extern __shared__ unsigned char lds[];
    const int slice = blockIdx.x;                // 0..509
    const int b = slice / 255, t = slice % 255;
    const int tid = threadIdx.x, w = tid >> 6, l = tid & 63;
    const int lm = l & 15, lk = l >> 4;
    const int rg = (w >> 1) * 16;                // row group (8 x 16 rows)
    const int cs = w & 1;                        // col strip (2 x 144 cols)

    // ---- phase 1: S (p=0) and R'+P (p=1) into LDS ----
#pragma unroll
    for (int p = 0; p < 2; p++) {
        const size_t abase =
            ((size_t)((b * 256 + t + 1 - p) * 128 + rg + lm)) * 256 + p * 128;
        f32x4 acc[9];
#pragma unroll
        for (int nf = 0; nf < 9; nf++) acc[nf] = (f32x4){0.f, 0.f, 0.f, 0.f};
#pragma unroll
        for (int ks = 0; ks < 4; ks++) {
            const bf16x8 a = *reinterpret_cast<const bf16x8*>(
                h2 + abase + ks * 32 + lk * 8);
#pragma unroll
            for (int nf = 0; nf < 9; nf++) {
                const bf16x8 bfr = *reinterpret_cast<const bf16x8*>(
                    wg3f + (size_t)p * 36864 +
                    (size_t)(ks * 18 + cs * 9 + nf) * 512 + l * 8);
                acc[nf] = __builtin_amdgcn_mfma_f32_16x16x32_bf16(a, bfr, acc[nf], 0, 0, 0);
            }
        }
#pragma unroll
        for (int nf = 0; nf < 9; nf++) {
            const int col  = cs * 144 + nf * 16 + lm;
            const float pa = p ? Pt[(size_t)t * 288 + col] : 0.f;
            const int base = p * SR_HALF + (col >> 1) * QCS + (col & 1) * 2;
#pragma unroll
            for (int reg = 0; reg < 4; reg++) {
                const int row = rg + lk * 4 + reg;
                *reinterpret_cast<unsigned short*>(lds + base + row * 4) =
                    f2bf(acc[nf][reg] + pa);
            }
        }
    }

    bf16x8 bfrag[9];
#pragma unroll
    for (int ks = 0; ks < 9; ks++)
        bfrag[ks] = *reinterpret_cast<const bf16x8*>(wc2f + (ks * 64 + l) * 8);
    const float bias = (lm < 5) ? bc2[lm] : 0.f;

    __syncthreads();

    // ---- phase 2: gather + relu + head (4 tiles of 16 edges per wave) ----
    for (int it = 0; it < 4; it++) {
        const int e0 = (w * 4 + it) * 16;
        const unsigned char* sb = lds + (unsigned)se[e0 + lm] * 4;
        const unsigned char* rb = lds + SR_HALF + (unsigned)re[e0 + lm] * 4;
        f32x4 acc = {0.f, 0.f, 0.f, 0.f};
#pragma unroll
        for (int ks = 0; ks < 9; ks++) {
            u32x4 hw;
#pragma unroll
            for (int i = 0; i < 4; i++) {
                const int off = (ks * 16 + lk * 4 + i) * QCS;
                const unsigned sw = *reinterpret_cast<const unsigned*>(sb + off);
                const unsigned rw = *reinterpret_cast<const unsigned*>(rb + off);
                const float lo = fmaxf(__builtin_bit_cast(float, sw << 16) +
                                       __builtin_bit_cast(float, rw << 16), 0.f);
                const float hi = fmaxf(__builtin_bit_cast(float, sw & 0xffff0000u) +
                                       __builtin_bit_cast(float, rw & 0xffff0000u), 0.f);
                unsigned pk;
                asm("v_cvt_pk_bf16_f32 %0, %1, %2" : "=v"(pk) : "v"(lo), "v"(hi));
                hw[i] = pk;
            }
            acc = __builtin_amdgcn_mfma_f32_16x16x32_bf16(
                __builtin_bit_cast(bf16x8, hw), bfrag[ks], acc, 0, 0, 0);
        }
        if (lm < 5) {
            float* op = out + ((size_t)slice * 1024 + e0 + lk * 4) * 5 + lm;
            op[0]  = acc[0] + bias;
            op[5]  = acc[1] + bias;
            op[10] = acc[2] + bias;
            op[15] = acc[3] + bias;
        }
    }
}

// ---------------------------------------------------------------------------
extern "C" void kernel_launch(void* const* d_in, const int* in_sizes, int n_in,
                              void* d_out, int out_size, void* d_ws, size_t ws_size,
                              hipStream_t stream)
{
    const float* spikes = (const float*)d_in[0];
    const float* W_emb  = (const float*)d_in[1];
    const float* b_emb  = (const float*)d_in[2];
    const float* Ws1    = (const float*)d_in[3];
    const float* bs1    = (const float*)d_in[4];
    const float* Ws2    = (const float*)d_in[5];
    const float* bs2    = (const float*)d_in[6];
    const float* Wr1    = (const float*)d_in[7];
    const float* br1    = (const float*)d_in[8];
    const float* Wr2    = (const float*)d_in[9];
    const float* br2    = (const float*)d_in[10];
    const float* Wc1    = (const float*)d_in[11];
    const float* bc1    = (const float*)d_in[12];
    const float* Wc2    = (const float*)d_in[13];
    const float* bc2    = (const float*)d_in[14];
    const int*   se     = (const int*)d_in[15];
    const int*   re     = (const int*)d_in[16];

    float* out = (float*)d_out;
    float* ws  = (float*)d_ws;

    // workspace layout (float offsets, all 16B-aligned):
    float*          P     = ws;                                   // 73,440 f
    float*          bias1 = ws + 73440;                           // 256 f
    float*          bias2 = ws + 73696;                           // 256 f
    unsigned short* wg1f  = (unsigned short*)(ws + 73952);        // 8,192 u16
    unsigned short* wg2f  = (unsigned short*)(ws + 78048);        // 32,768 u16
    unsigned short* wg3f  = (unsigned short*)(ws + 94432);        // 73,728 u16
    unsigned short* wc2f  = (unsigned short*)(ws + 131296);       // 4,608 u16
    unsigned short* h2    = (unsigned short*)(ws + 133600);       // 65536*256 u16

    const dim3 blk(256);

    (void)hipFuncSetAttribute(reinterpret_cast<const void*>(final3),
                              hipFuncAttributeMaxDynamicSharedMemorySize, LDS_B);

    prep_kernel<<<756, blk, 0, stream>>>(
        W_emb, b_emb, Ws1, bs1, Wr1, br1, Ws2, bs2, Wr2, br2, Wc1, bc1, Wc2,
        P, bias1, bias2, wg1f, wg2f, wg3f, wc2f);

    // h2 = relu(relu(spikes @ wg1 + bias1) @ diag(Ws2,Wr2) + bias2)
    fused12<<<1024, blk, 0, stream>>>(spikes, wg1f, bias1, wg2f, bias2, h2);

    // per-slice: SR into LDS + gather + head
    final3<<<510, dim3(1024), LDS_B, stream>>>(h2, wg3f, P, wc2f, bc2, se, re, out);
}

// Round 7
// 88.403 us; speedup vs baseline: 5.9569x; 1.0693x over previous
//
#include <hip/hip_runtime.h>
#include <hip/hip_bf16.h>
#include <cstdint>
#include <cstddef>

typedef __attribute__((ext_vector_type(8))) short bf16x8;
typedef __attribute__((ext_vector_type(4))) float f32x4;
typedef __attribute__((ext_vector_type(4))) unsigned u32x4;

__device__ inline unsigned short f2bf(float f) {   // RNE
    __hip_bfloat16 h = __float2bfloat16(f);
    return __builtin_bit_cast(unsigned short, h);
}
__device__ inline unsigned cvtpk(float lo, float hi) {
    unsigned pk;
    asm("v_cvt_pk_bf16_f32 %0, %1, %2" : "=v"(pk) : "v"(lo), "v"(hi));
    return pk;
}

// ---------------------------------------------------------------------------
// One-shot prep: P (PE@Wc1 + bc1), folded first-layer weights/biases, and all
// weights converted to bf16 MFMA fragments.
// B-fragment order (wg1f/wg2f/wc2f): frag[f*512+l*8+j] = W[ks*32+(l>>4)*8+j][nf*16+(l&15)]
// A-fragment order (wg3fT, transposed): frag[((p*18+mt)*4+ks)*512+l*8+j]
//   = Wc1[p*144 + ks*32+(l>>4)*8+j][mt*16+(l&15)]
// ---------------------------------------------------------------------------
__global__ void prep_kernel(
    const float* __restrict__ W_emb, const float* __restrict__ b_emb,
    const float* __restrict__ Ws1, const float* __restrict__ bs1,
    const float* __restrict__ Wr1, const float* __restrict__ br1,
    const float* __restrict__ Ws2, const float* __restrict__ bs2,
    const float* __restrict__ Wr2, const float* __restrict__ br2,
    const float* __restrict__ Wc1, const float* __restrict__ bc1,
    const float* __restrict__ Wc2,
    float* __restrict__ P, float* __restrict__ bias1, float* __restrict__ bias2,
    unsigned short* __restrict__ wg1f, unsigned short* __restrict__ wg2f,
    unsigned short* __restrict__ wg3fT, unsigned short* __restrict__ wc2f)
{
    int id = blockIdx.x * 256 + threadIdx.x;

    if (id < 73440) {   // P[t,h] = pe[t+1]@Wc1[128:144] + pe[t]@Wc1[272:288] + bc1
        const int t = id / 288, ho = id % 288;
        float acc = bc1[ho];
#pragma unroll
        for (int i = 0; i < 8; i++) {
            const float div = expf(-1.1512925464970229f * (float)i);
            const float a1 = (float)(t + 1) * div;
            const float a0 = (float)t * div;
            acc += sinf(a1) * Wc1[(size_t)(128 + 2 * i) * 288 + ho];
            acc += cosf(a1) * Wc1[(size_t)(129 + 2 * i) * 288 + ho];
            acc += sinf(a0) * Wc1[(size_t)(272 + 2 * i) * 288 + ho];
            acc += cosf(a0) * Wc1[(size_t)(273 + 2 * i) * 288 + ho];
        }
        P[id] = acc;
        return;
    }
    id -= 73440;

    if (id < 8192) {    // wg1f: [W_emb@Ws1 | W_emb@Wr1], K padded 16->32
        const int y = id >> 12, r = id & 4095;
        const int f = r >> 9, l = (r >> 3) & 63, j = r & 7;
        const int k = ((l >> 4) << 3) + j;          // 0..31
        const int n = f * 16 + (l & 15);
        float v = 0.f;
        if (k < 16) {
            const float* Wx = y ? Wr1 : Ws1;
            for (int d = 0; d < 128; d++) v += W_emb[k * 128 + d] * Wx[d * 128 + n];
        }
        wg1f[id] = f2bf(v);
        return;
    }
    id -= 8192;

    if (id < 256) {     // bias1 = [bs1 + b_emb@Ws1 | br1 + b_emb@Wr1]
        const int y = id >> 7, c = id & 127;
        const float* Wx = y ? Wr1 : Ws1;
        float v = (y ? br1 : bs1)[c];
        for (int d = 0; d < 128; d++) v += b_emb[d] * Wx[d * 128 + c];
        bias1[id] = v;
        return;
    }
    id -= 256;

    if (id < 32768) {   // wg2f: [Ws2 | Wr2] fragments
        const int y = id >> 14, r = id & 16383;
        const int f = r >> 9, l = (r >> 3) & 63, j = r & 7;
        const int ks = f >> 3, nf = f & 7;
        const int k = ks * 32 + ((l >> 4) << 3) + j;
        const int n = nf * 16 + (l & 15);
        wg2f[id] = f2bf((y ? Wr2 : Ws2)[(size_t)k * 128 + n]);
        return;
    }
    id -= 32768;

    if (id < 256) {     // bias2 = [bs2 | br2]
        bias2[id] = (id < 128) ? bs2[id] : br2[id - 128];
        return;
    }
    id -= 256;

    if (id < 73728) {   // wg3fT: transposed A-fragments of [Wc1a | Wc1b]
        const int p = id / 36864, r = id % 36864;
        const int frag = r >> 9, l = (r >> 3) & 63, j = r & 7;
        const int mt = frag >> 2, ks = frag & 3;
        const int k = ks * 32 + ((l >> 4) << 3) + j;     // Wc1 row (K dim)
        const int n = mt * 16 + (l & 15);                // Wc1 col (output)
        wg3fT[id] = f2bf(Wc1[(size_t)(p * 144 + k) * 288 + n]);
        return;
    }
    id -= 73728;

    if (id < 4608) {    // wc2f: head weight fragments (288x5 padded to 16 cols)
        const int j = id & 7, l = (id >> 3) & 63, ks = id >> 9;
        const int k = ks * 32 + ((l >> 4) << 3) + j;
        const int c = l & 15;
        wc2f[id] = (c < 5) ? f2bf(Wc2[(size_t)k * 5 + c]) : (unsigned short)0;
    }
}

// ---------------------------------------------------------------------------
// Kernel A: h2 = relu( relu(spikes @ wg1 + bias1) @ diag(Ws2,Wr2) + bias2 )
// 64 rows/block, 4 waves (2 row x 2 col). h1 lives in LDS.
// ---------------------------------------------------------------------------
#define H1S 264   // shorts per h1 LDS row

__global__ __launch_bounds__(256) void fused12(
    const float* __restrict__ spikes,
    const unsigned short* __restrict__ wg1f, const float* __restrict__ bias1,
    const unsigned short* __restrict__ wg2f, const float* __restrict__ bias2,
    unsigned short* __restrict__ h2)
{
    __shared__ unsigned short h1l[64 * H1S];     // 33,792 B
    const int row0 = blockIdx.x * 64;
    const int tid = threadIdx.x;
    const int w = tid >> 6, l = tid & 63;
    const int wm = w >> 1, wn = w & 1;
    const int lm = l & 15, lk = l >> 4;
    const int wrow = wm * 32;                    // local row base

    // ---- stage 0: h1 = relu(spikes @ wg1 + bias1), K=16 padded to 32 ----
    bf16x8 a0[2];
#pragma unroll
    for (int rf = 0; rf < 2; rf++) {
        bf16x8 tv = {0, 0, 0, 0, 0, 0, 0, 0};
        if (lk < 2) {
            const float* p = spikes + (size_t)(row0 + wrow + rf * 16 + lm) * 16 + lk * 8;
            const float4 v0 = *reinterpret_cast<const float4*>(p);
            const float4 v1 = *reinterpret_cast<const float4*>(p + 4);
            tv[0] = (short)f2bf(v0.x); tv[1] = (short)f2bf(v0.y);
            tv[2] = (short)f2bf(v0.z); tv[3] = (short)f2bf(v0.w);
            tv[4] = (short)f2bf(v1.x); tv[5] = (short)f2bf(v1.y);
            tv[6] = (short)f2bf(v1.z); tv[7] = (short)f2bf(v1.w);
        }
        a0[rf] = tv;
    }
    f32x4 acc[2][8];
#pragma unroll
    for (int rf = 0; rf < 2; rf++)
#pragma unroll
        for (int nf = 0; nf < 8; nf++) acc[rf][nf] = (f32x4){0.f, 0.f, 0.f, 0.f};

#pragma unroll
    for (int nf = 0; nf < 8; nf++) {
        const bf16x8 bfr = *reinterpret_cast<const bf16x8*>(
            wg1f + (size_t)(wn * 8 + nf) * 512 + l * 8);
        acc[0][nf] = __builtin_amdgcn_mfma_f32_16x16x32_bf16(a0[0], bfr, acc[0][nf], 0, 0, 0);
        acc[1][nf] = __builtin_amdgcn_mfma_f32_16x16x32_bf16(a0[1], bfr, acc[1][nf], 0, 0, 0);
    }
#pragma unroll
    for (int rf = 0; rf < 2; rf++)
#pragma unroll
        for (int nf = 0; nf < 8; nf++) {
            const int gc = wn * 128 + nf * 16 + lm;
            const float add = bias1[gc];
#pragma unroll
            for (int reg = 0; reg < 4; reg++) {
                const int r = wrow + rf * 16 + lk * 4 + reg;
                h1l[r * H1S + gc] = f2bf(fmaxf(acc[rf][nf][reg] + add, 0.f));
            }
        }
    __syncthreads();

    // ---- stage 1: h2 = relu(h1 @ diag(Ws2,Wr2) + bias2), K=128 per half ----
#pragma unroll
    for (int rf = 0; rf < 2; rf++)
#pragma unroll
        for (int nf = 0; nf < 8; nf++) acc[rf][nf] = (f32x4){0.f, 0.f, 0.f, 0.f};

#pragma unroll
    for (int ks = 0; ks < 4; ks++) {
        bf16x8 a[2];
        a[0] = *reinterpret_cast<const bf16x8*>(
            &h1l[(wrow + lm) * H1S + wn * 128 + ks * 32 + lk * 8]);
        a[1] = *reinterpret_cast<const bf16x8*>(
            &h1l[(wrow + 16 + lm) * H1S + wn * 128 + ks * 32 + lk * 8]);
#pragma unroll
        for (int nf = 0; nf < 8; nf++) {
            const bf16x8 bfr = *reinterpret_cast<const bf16x8*>(
                wg2f + (size_t)wn * 16384 + (size_t)(ks * 8 + nf) * 512 + l * 8);
            acc[0][nf] = __builtin_amdgcn_mfma_f32_16x16x32_bf16(a[0], bfr, acc[0][nf], 0, 0, 0);
            acc[1][nf] = __builtin_amdgcn_mfma_f32_16x16x32_bf16(a[1], bfr, acc[1][nf], 0, 0, 0);
        }
    }
#pragma unroll
    for (int rf = 0; rf < 2; rf++)
#pragma unroll
        for (int nf = 0; nf < 8; nf++) {
            const int gc = wn * 128 + nf * 16 + lm;
            const float add = bias2[gc];
#pragma unroll
            for (int reg = 0; reg < 4; reg++) {
                const size_t r = (size_t)(row0 + wrow + rf * 16 + lk * 4 + reg);
                h2[r * 256 + gc] = f2bf(fmaxf(acc[rf][nf][reg] + add, 0.f));
            }
        }
}

// ---------------------------------------------------------------------------
// Kernel B: per (b,t) slice.
// Phase 1 (transposed): S^T-tiles = mfma(A=Wc1^T frags, B=h2-row frags).
// D mapping: col(lane&15) = h2 row, row(lk*4+reg) = 4 CONSECUTIVE Wc1 cols
// -> pack 4 accs into 2 dwords (v_cvt_pk_bf16_f32) -> one ds_write_b64 into
// row-major LDS tile [128 rows][576 B], byte = r*576 + ((2c) ^ ((r&3)<<4)).
// Phase 2: per 16-edge tile, gather rows with ds_read_b128 (8 k's per lane,
// same swizzle), h = relu(S+R) via cvt_pk, 9 MFMA 16x16x32 -> out.
// ---------------------------------------------------------------------------
#define SROWB  576
#define SMATB  73728     // 128 * 576
#define LDS_B2 147456    // 2 * SMATB

__global__ __launch_bounds__(1024) void final4(
    const unsigned short* __restrict__ h2,
    const unsigned short* __restrict__ wg3fT, const float* __restrict__ Pt,
    const unsigned short* __restrict__ wc2f, const float* __restrict__ bc2,
    const int* __restrict__ se, const int* __restrict__ re,
    float* __restrict__ out)
{
    extern __shared__ unsigned char lds[];
    const int slice = blockIdx.x;                // 0..509
    const int b = slice / 255, t = slice % 255;
    const int tid = threadIdx.x, w = tid >> 6, l = tid & 63;
    const int lm = l & 15, lk = l >> 4;
    const int nt = w & 7;                        // h2-row tile (8 x 16 rows)
    const int wg = w >> 3;                       // Wc1-col half (2 x 9 tiles)

    // ---- phase 1: S (p=0) and R'+P (p=1) into LDS, transposed MFMA ----
    const int r  = nt * 16 + lm;                 // h2 row this lane's D col maps to
    const int xw = (r & 3) << 4;
#pragma unroll
    for (int p = 0; p < 2; p++) {
        const size_t hbase =
            ((size_t)((b * 256 + t + 1 - p) * 128 + r)) * 256 + p * 128 + lk * 8;
        bf16x8 bfr[4];
#pragma unroll
        for (int ks = 0; ks < 4; ks++)
            bfr[ks] = *reinterpret_cast<const bf16x8*>(h2 + hbase + ks * 32);
        unsigned char* mbase = lds + p * SMATB + r * SROWB;
#pragma unroll
        for (int m9 = 0; m9 < 9; m9++) {
            const int mt = wg * 9 + m9;
            f32x4 acc = {0.f, 0.f, 0.f, 0.f};
#pragma unroll
            for (int ks = 0; ks < 4; ks++) {
                const bf16x8 afr = *reinterpret_cast<const bf16x8*>(
                    wg3fT + ((size_t)(((p * 18 + mt) << 2) + ks) << 9) + l * 8);
                acc = __builtin_amdgcn_mfma_f32_16x16x32_bf16(afr, bfr[ks], acc, 0, 0, 0);
            }
            const int c0 = mt * 16 + lk * 4;
            float4 pa = {0.f, 0.f, 0.f, 0.f};
            if (p) pa = *reinterpret_cast<const float4*>(Pt + (size_t)t * 288 + c0);
            uint2 wv;
            wv.x = cvtpk(acc[0] + pa.x, acc[1] + pa.y);
            wv.y = cvtpk(acc[2] + pa.z, acc[3] + pa.w);
            *reinterpret_cast<uint2*>(mbase + (((mt * 32 + lk * 8) ^ xw))) = wv;
        }
    }

    bf16x8 bfrag[9];
#pragma unroll
    for (int ks = 0; ks < 9; ks++)
        bfrag[ks] = *reinterpret_cast<const bf16x8*>(wc2f + (ks * 64 + l) * 8);
    const float bias = (lm < 5) ? bc2[lm] : 0.f;

    __syncthreads();

    // ---- phase 2: gather + relu + head (4 tiles of 16 edges per wave) ----
    for (int it = 0; it < 4; it++) {
        const int e0  = (w * 4 + it) * 16;
        const int srw = se[e0 + lm];
        const int rrw = re[e0 + lm];
        const unsigned char* sb = lds + srw * SROWB + ((lk * 16) ^ ((srw & 3) << 4));
        const unsigned char* rb = lds + SMATB + rrw * SROWB + ((lk * 16) ^ ((rrw & 3) << 4));
        f32x4 acc = {0.f, 0.f, 0.f, 0.f};
#pragma unroll
        for (int ks = 0; ks < 9; ks++) {
            const u32x4 s4 = *reinterpret_cast<const u32x4*>(sb + ks * 64);
            const u32x4 r4 = *reinterpret_cast<const u32x4*>(rb + ks * 64);
            u32x4 hw;
#pragma unroll
            for (int i = 0; i < 4; i++) {
                const unsigned sw = s4[i], rw = r4[i];
                const float lo = fmaxf(__builtin_bit_cast(float, sw << 16) +
                                       __builtin_bit_cast(float, rw << 16), 0.f);
                const float hi = fmaxf(__builtin_bit_cast(float, sw & 0xffff0000u) +
                                       __builtin_bit_cast(float, rw & 0xffff0000u), 0.f);
                hw[i] = cvtpk(lo, hi);
            }
            acc = __builtin_amdgcn_mfma_f32_16x16x32_bf16(
                __builtin_bit_cast(bf16x8, hw), bfrag[ks], acc, 0, 0, 0);
        }
        if (lm < 5) {
            float* op = out + ((size_t)slice * 1024 + e0 + lk * 4) * 5 + lm;
            op[0]  = acc[0] + bias;
            op[5]  = acc[1] + bias;
            op[10] = acc[2] + bias;
            op[15] = acc[3] + bias;
        }
    }
}

// ---------------------------------------------------------------------------
extern "C" void kernel_launch(void* const* d_in, const int* in_sizes, int n_in,
                              void* d_out, int out_size, void* d_ws, size_t ws_size,
                              hipStream_t stream)
{
    const float* spikes = (const float*)d_in[0];
    const float* W_emb  = (const float*)d_in[1];
    const float* b_emb  = (const float*)d_in[2];
    const float* Ws1    = (const float*)d_in[3];
    const float* bs1    = (const float*)d_in[4];
    const float* Ws2    = (const float*)d_in[5];
    const float* bs2    = (const float*)d_in[6];
    const float* Wr1    = (const float*)d_in[7];
    const float* br1    = (const float*)d_in[8];
    const float* Wr2    = (const float*)d_in[9];
    const float* br2    = (const float*)d_in[10];
    const float* Wc1    = (const float*)d_in[11];
    const float* bc1    = (const float*)d_in[12];
    const float* Wc2    = (const float*)d_in[13];
    const float* bc2    = (const float*)d_in[14];
    const int*   se     = (const int*)d_in[15];
    const int*   re     = (const int*)d_in[16];

    float* out = (float*)d_out;
    float* ws  = (float*)d_ws;

    // workspace layout (float offsets, all 16B-aligned):
    float*          P     = ws;                                   // 73,440 f
    float*          bias1 = ws + 73440;                           // 256 f
    float*          bias2 = ws + 73696;                           // 256 f
    unsigned short* wg1f  = (unsigned short*)(ws + 73952);        // 8,192 u16
    unsigned short* wg2f  = (unsigned short*)(ws + 78048);        // 32,768 u16
    unsigned short* wg3fT = (unsigned short*)(ws + 94432);        // 73,728 u16
    unsigned short* wc2f  = (unsigned short*)(ws + 131296);       // 4,608 u16
    unsigned short* h2    = (unsigned short*)(ws + 133600);       // 65536*256 u16

    const dim3 blk(256);

    (void)hipFuncSetAttribute(reinterpret_cast<const void*>(final4),
                              hipFuncAttributeMaxDynamicSharedMemorySize, LDS_B2);

    prep_kernel<<<756, blk, 0, stream>>>(
        W_emb, b_emb, Ws1, bs1, Wr1, br1, Ws2, bs2, Wr2, br2, Wc1, bc1, Wc2,
        P, bias1, bias2, wg1f, wg2f, wg3fT, wc2f);

    // h2 = relu(relu(spikes @ wg1 + bias1) @ diag(Ws2,Wr2) + bias2)
    fused12<<<1024, blk, 0, stream>>>(spikes, wg1f, bias1, wg2f, bias2, h2);

    // per-slice: transposed SR into LDS + gather + head
    final4<<<510, dim3(1024), LDS_B2, stream>>>(h2, wg3fT, P, wc2f, bc2, se, re, out);
}

// Round 8
// 80.758 us; speedup vs baseline: 6.5208x; 1.0947x over previous
//
#include <hip/hip_runtime.h>
#include <hip/hip_bf16.h>
#include <cstdint>
#include <cstddef>

typedef __attribute__((ext_vector_type(8))) short bf16x8;
typedef __attribute__((ext_vector_type(4))) float f32x4;
typedef __attribute__((ext_vector_type(4))) unsigned u32x4;

__device__ inline unsigned short f2bf(float f) {   // RNE
    __hip_bfloat16 h = __float2bfloat16(f);
    return __builtin_bit_cast(unsigned short, h);
}
__device__ inline unsigned cvtpk(float lo, float hi) {
    unsigned pk;
    asm("v_cvt_pk_bf16_f32 %0, %1, %2" : "=v"(pk) : "v"(lo), "v"(hi));
    return pk;
}

// ---------------------------------------------------------------------------
// One-shot prep: P (PE@Wc1 + bc1), folded first-layer weights/biases, and all
// weights converted to bf16 MFMA fragments.
// B-fragment order (wg1f/wg2f/wc2f): frag[f*512+l*8+j] = W[ks*32+(l>>4)*8+j][nf*16+(l&15)]
// A-fragment order (wg3fT, transposed): frag[((p*18+mt)*4+ks)*512+l*8+j]
//   = Wc1[p*144 + ks*32+(l>>4)*8+j][mt*16+(l&15)]
// ---------------------------------------------------------------------------
__global__ void prep_kernel(
    const float* __restrict__ W_emb, const float* __restrict__ b_emb,
    const float* __restrict__ Ws1, const float* __restrict__ bs1,
    const float* __restrict__ Wr1, const float* __restrict__ br1,
    const float* __restrict__ Ws2, const float* __restrict__ bs2,
    const float* __restrict__ Wr2, const float* __restrict__ br2,
    const float* __restrict__ Wc1, const float* __restrict__ bc1,
    const float* __restrict__ Wc2,
    float* __restrict__ P, float* __restrict__ bias1, float* __restrict__ bias2,
    unsigned short* __restrict__ wg1f, unsigned short* __restrict__ wg2f,
    unsigned short* __restrict__ wg3fT, unsigned short* __restrict__ wc2f)
{
    int id = blockIdx.x * 256 + threadIdx.x;

    if (id < 73440) {   // P[t,h] = pe[t+1]@Wc1[128:144] + pe[t]@Wc1[272:288] + bc1
        const int t = id / 288, ho = id % 288;
        float acc = bc1[ho];
#pragma unroll
        for (int i = 0; i < 8; i++) {
            const float div = expf(-1.1512925464970229f * (float)i);
            const float a1 = (float)(t + 1) * div;
            const float a0 = (float)t * div;
            acc += sinf(a1) * Wc1[(size_t)(128 + 2 * i) * 288 + ho];
            acc += cosf(a1) * Wc1[(size_t)(129 + 2 * i) * 288 + ho];
            acc += sinf(a0) * Wc1[(size_t)(272 + 2 * i) * 288 + ho];
            acc += cosf(a0) * Wc1[(size_t)(273 + 2 * i) * 288 + ho];
        }
        P[id] = acc;
        return;
    }
    id -= 73440;

    if (id < 8192) {    // wg1f: [W_emb@Ws1 | W_emb@Wr1], K padded 16->32
        const int y = id >> 12, r = id & 4095;
        const int f = r >> 9, l = (r >> 3) & 63, j = r & 7;
        const int k = ((l >> 4) << 3) + j;          // 0..31
        const int n = f * 16 + (l & 15);
        float v = 0.f;
        if (k < 16) {
            const float* Wx = y ? Wr1 : Ws1;
            for (int d = 0; d < 128; d++) v += W_emb[k * 128 + d] * Wx[d * 128 + n];
        }
        wg1f[id] = f2bf(v);
        return;
    }
    id -= 8192;

    if (id < 256) {     // bias1 = [bs1 + b_emb@Ws1 | br1 + b_emb@Wr1]
        const int y = id >> 7, c = id & 127;
        const float* Wx = y ? Wr1 : Ws1;
        float v = (y ? br1 : bs1)[c];
        for (int d = 0; d < 128; d++) v += b_emb[d] * Wx[d * 128 + c];
        bias1[id] = v;
        return;
    }
    id -= 256;

    if (id < 32768) {   // wg2f: [Ws2 | Wr2] fragments
        const int y = id >> 14, r = id & 16383;
        const int f = r >> 9, l = (r >> 3) & 63, j = r & 7;
        const int ks = f >> 3, nf = f & 7;
        const int k = ks * 32 + ((l >> 4) << 3) + j;
        const int n = nf * 16 + (l & 15);
        wg2f[id] = f2bf((y ? Wr2 : Ws2)[(size_t)k * 128 + n]);
        return;
    }
    id -= 32768;

    if (id < 256) {     // bias2 = [bs2 | br2]
        bias2[id] = (id < 128) ? bs2[id] : br2[id - 128];
        return;
    }
    id -= 256;

    if (id < 73728) {   // wg3fT: transposed A-fragments of [Wc1a | Wc1b]
        const int p = id / 36864, r = id % 36864;
        const int frag = r >> 9, l = (r >> 3) & 63, j = r & 7;
        const int mt = frag >> 2, ks = frag & 3;
        const int k = ks * 32 + ((l >> 4) << 3) + j;     // Wc1 row (K dim)
        const int n = mt * 16 + (l & 15);                // Wc1 col (output)
        wg3fT[id] = f2bf(Wc1[(size_t)(p * 144 + k) * 288 + n]);
        return;
    }
    id -= 73728;

    if (id < 4608) {    // wc2f: head weight fragments (288x5 padded to 16 cols)
        const int j = id & 7, l = (id >> 3) & 63, ks = id >> 9;
        const int k = ks * 32 + ((l >> 4) << 3) + j;
        const int c = l & 15;
        wc2f[id] = (c < 5) ? f2bf(Wc2[(size_t)k * 5 + c]) : (unsigned short)0;
    }
}

// ---------------------------------------------------------------------------
// Kernel A: h2 = relu( relu(spikes @ wg1 + bias1) @ diag(Ws2,Wr2) + bias2 )
// 64 rows/block, 4 waves (2 row x 2 col). h1 lives in LDS.
// ---------------------------------------------------------------------------
#define H1S 264   // shorts per h1 LDS row

__global__ __launch_bounds__(256) void fused12(
    const float* __restrict__ spikes,
    const unsigned short* __restrict__ wg1f, const float* __restrict__ bias1,
    const unsigned short* __restrict__ wg2f, const float* __restrict__ bias2,
    unsigned short* __restrict__ h2)
{
    __shared__ unsigned short h1l[64 * H1S];     // 33,792 B
    const int row0 = blockIdx.x * 64;
    const int tid = threadIdx.x;
    const int w = tid >> 6, l = tid & 63;
    const int wm = w >> 1, wn = w & 1;
    const int lm = l & 15, lk = l >> 4;
    const int wrow = wm * 32;                    // local row base

    // ---- stage 0: h1 = relu(spikes @ wg1 + bias1), K=16 padded to 32 ----
    bf16x8 a0[2];
#pragma unroll
    for (int rf = 0; rf < 2; rf++) {
        bf16x8 tv = {0, 0, 0, 0, 0, 0, 0, 0};
        if (lk < 2) {
            const float* p = spikes + (size_t)(row0 + wrow + rf * 16 + lm) * 16 + lk * 8;
            const float4 v0 = *reinterpret_cast<const float4*>(p);
            const float4 v1 = *reinterpret_cast<const float4*>(p + 4);
            tv[0] = (short)f2bf(v0.x); tv[1] = (short)f2bf(v0.y);
            tv[2] = (short)f2bf(v0.z); tv[3] = (short)f2bf(v0.w);
            tv[4] = (short)f2bf(v1.x); tv[5] = (short)f2bf(v1.y);
            tv[6] = (short)f2bf(v1.z); tv[7] = (short)f2bf(v1.w);
        }
        a0[rf] = tv;
    }
    f32x4 acc[2][8];
#pragma unroll
    for (int rf = 0; rf < 2; rf++)
#pragma unroll
        for (int nf = 0; nf < 8; nf++) acc[rf][nf] = (f32x4){0.f, 0.f, 0.f, 0.f};

#pragma unroll
    for (int nf = 0; nf < 8; nf++) {
        const bf16x8 bfr = *reinterpret_cast<const bf16x8*>(
            wg1f + (size_t)(wn * 8 + nf) * 512 + l * 8);
        acc[0][nf] = __builtin_amdgcn_mfma_f32_16x16x32_bf16(a0[0], bfr, acc[0][nf], 0, 0, 0);
        acc[1][nf] = __builtin_amdgcn_mfma_f32_16x16x32_bf16(a0[1], bfr, acc[1][nf], 0, 0, 0);
    }
#pragma unroll
    for (int rf = 0; rf < 2; rf++)
#pragma unroll
        for (int nf = 0; nf < 8; nf++) {
            const int gc = wn * 128 + nf * 16 + lm;
            const float add = bias1[gc];
#pragma unroll
            for (int reg = 0; reg < 4; reg++) {
                const int r = wrow + rf * 16 + lk * 4 + reg;
                h1l[r * H1S + gc] = f2bf(fmaxf(acc[rf][nf][reg] + add, 0.f));
            }
        }
    __syncthreads();

    // ---- stage 1: h2 = relu(h1 @ diag(Ws2,Wr2) + bias2), K=128 per half ----
#pragma unroll
    for (int rf = 0; rf < 2; rf++)
#pragma unroll
        for (int nf = 0; nf < 8; nf++) acc[rf][nf] = (f32x4){0.f, 0.f, 0.f, 0.f};

#pragma unroll
    for (int ks = 0; ks < 4; ks++) {
        bf16x8 a[2];
        a[0] = *reinterpret_cast<const bf16x8*>(
            &h1l[(wrow + lm) * H1S + wn * 128 + ks * 32 + lk * 8]);
        a[1] = *reinterpret_cast<const bf16x8*>(
            &h1l[(wrow + 16 + lm) * H1S + wn * 128 + ks * 32 + lk * 8]);
#pragma unroll
        for (int nf = 0; nf < 8; nf++) {
            const bf16x8 bfr = *reinterpret_cast<const bf16x8*>(
                wg2f + (size_t)wn * 16384 + (size_t)(ks * 8 + nf) * 512 + l * 8);
            acc[0][nf] = __builtin_amdgcn_mfma_f32_16x16x32_bf16(a[0], bfr, acc[0][nf], 0, 0, 0);
            acc[1][nf] = __builtin_amdgcn_mfma_f32_16x16x32_bf16(a[1], bfr, acc[1][nf], 0, 0, 0);
        }
    }
#pragma unroll
    for (int rf = 0; rf < 2; rf++)
#pragma unroll
        for (int nf = 0; nf < 8; nf++) {
            const int gc = wn * 128 + nf * 16 + lm;
            const float add = bias2[gc];
#pragma unroll
            for (int reg = 0; reg < 4; reg++) {
                const size_t r = (size_t)(row0 + wrow + rf * 16 + lk * 4 + reg);
                h2[r * 256 + gc] = f2bf(fmaxf(acc[rf][nf][reg] + add, 0.f));
            }
        }
}

// ---------------------------------------------------------------------------
// Kernel B: per (b,t) slice.
// Phase 1 (transposed): S^T/R'^T tiles = mfma(A=Wc1^T frags, B=h2-row frags).
// Wave = (rowg 0..3) x (colg 0..3): 32 h2 rows (2 B-frag sets), 9 col-tiles,
// p = colg>>1. Weight fragments read once per 32 output rows (half the L2
// traffic of the 16-row scheme).
// LDS: row-major [128 rows][592 B] per matrix. 592 = 37*16; 16B-block index
// = 37*row + cb, and 37 mod 8 = 5 (odd) -> random gathered rows spread
// uniformly over all 8 bank groups with NO xor swizzle; write and read use
// the same linear in-row byte map (both-sides-or-neither).
// Phase 2: per 16-edge tile, gather rows with ds_read_b128, h = relu(S+R)
// via v_cvt_pk_bf16_f32, 9 MFMA 16x16x32 -> out.
// ---------------------------------------------------------------------------
#define SROWB  592
#define SMATB  75776     // 128 * 592
#define LDS_B2 151552    // 2 * SMATB

__global__ __launch_bounds__(1024) void final4(
    const unsigned short* __restrict__ h2,
    const unsigned short* __restrict__ wg3fT, const float* __restrict__ Pt,
    const unsigned short* __restrict__ wc2f, const float* __restrict__ bc2,
    const int* __restrict__ se, const int* __restrict__ re,
    float* __restrict__ out)
{
    extern __shared__ unsigned char lds[];
    const int slice = blockIdx.x;                // 0..509
    const int b = slice / 255, t = slice % 255;
    const int tid = threadIdx.x, w = tid >> 6, l = tid & 63;
    const int lm = l & 15, lk = l >> 4;

    // ---- phase 1: S (p=0) and R'+P (p=1) into LDS, transposed MFMA ----
    {
        const int rowg = w & 3, colg = w >> 2;
        const int p  = colg >> 1;
        const int mtb = (colg & 1) * 9;
        const size_t hrow0 = (size_t)((b * 256 + t + 1 - p) * 128 + rowg * 32 + lm);

        bf16x8 bfr[2][4];
#pragma unroll
        for (int half = 0; half < 2; half++)
#pragma unroll
            for (int ks = 0; ks < 4; ks++)
                bfr[half][ks] = *reinterpret_cast<const bf16x8*>(
                    h2 + (hrow0 + half * 16) * 256 + p * 128 + ks * 32 + lk * 8);

        unsigned char* mb0 = lds + p * SMATB + (rowg * 32 + lm) * SROWB;
        unsigned char* mb1 = mb0 + 16 * SROWB;

#pragma unroll
        for (int m9 = 0; m9 < 9; m9++) {
            const int mt = mtb + m9;
            f32x4 acc0 = {0.f, 0.f, 0.f, 0.f};
            f32x4 acc1 = {0.f, 0.f, 0.f, 0.f};
#pragma unroll
            for (int ks = 0; ks < 4; ks++) {
                const bf16x8 afr = *reinterpret_cast<const bf16x8*>(
                    wg3fT + ((size_t)(((p * 18 + mt) << 2) + ks) << 9) + l * 8);
                acc0 = __builtin_amdgcn_mfma_f32_16x16x32_bf16(afr, bfr[0][ks], acc0, 0, 0, 0);
                acc1 = __builtin_amdgcn_mfma_f32_16x16x32_bf16(afr, bfr[1][ks], acc1, 0, 0, 0);
            }
            const int c0 = mt * 16 + lk * 4;
            float4 pa = {0.f, 0.f, 0.f, 0.f};
            if (p) pa = *reinterpret_cast<const float4*>(Pt + (size_t)t * 288 + c0);
            const int boff = mt * 32 + lk * 8;
            uint2 wv;
            wv.x = cvtpk(acc0[0] + pa.x, acc0[1] + pa.y);
            wv.y = cvtpk(acc0[2] + pa.z, acc0[3] + pa.w);
            *reinterpret_cast<uint2*>(mb0 + boff) = wv;
            wv.x = cvtpk(acc1[0] + pa.x, acc1[1] + pa.y);
            wv.y = cvtpk(acc1[2] + pa.z, acc1[3] + pa.w);
            *reinterpret_cast<uint2*>(mb1 + boff) = wv;
        }
    }

    bf16x8 bfrag[9];
#pragma unroll
    for (int ks = 0; ks < 9; ks++)
        bfrag[ks] = *reinterpret_cast<const bf16x8*>(wc2f + (ks * 64 + l) * 8);
    const float bias = (lm < 5) ? bc2[lm] : 0.f;

    __syncthreads();

    // ---- phase 2: gather + relu + head (4 tiles of 16 edges per wave) ----
    for (int it = 0; it < 4; it++) {
        const int e0  = (w * 4 + it) * 16;
        const int srw = se[e0 + lm];
        const int rrw = re[e0 + lm];
        const unsigned char* sb = lds + srw * SROWB + lk * 16;
        const unsigned char* rb = lds + SMATB + rrw * SROWB + lk * 16;
        f32x4 acc = {0.f, 0.f, 0.f, 0.f};
#pragma unroll
        for (int ks = 0; ks < 9; ks++) {
            const u32x4 s4 = *reinterpret_cast<const u32x4*>(sb + ks * 64);
            const u32x4 r4 = *reinterpret_cast<const u32x4*>(rb + ks * 64);
            u32x4 hw;
#pragma unroll
            for (int i = 0; i < 4; i++) {
                const unsigned sw = s4[i], rw = r4[i];
                const float lo = fmaxf(__builtin_bit_cast(float, sw << 16) +
                                       __builtin_bit_cast(float, rw << 16), 0.f);
                const float hi = fmaxf(__builtin_bit_cast(float, sw & 0xffff0000u) +
                                       __builtin_bit_cast(float, rw & 0xffff0000u), 0.f);
                hw[i] = cvtpk(lo, hi);
            }
            acc = __builtin_amdgcn_mfma_f32_16x16x32_bf16(
                __builtin_bit_cast(bf16x8, hw), bfrag[ks], acc, 0, 0, 0);
        }
        if (lm < 5) {
            float* op = out + ((size_t)slice * 1024 + e0 + lk * 4) * 5 + lm;
            op[0]  = acc[0] + bias;
            op[5]  = acc[1] + bias;
            op[10] = acc[2] + bias;
            op[15] = acc[3] + bias;
        }
    }
}

// ---------------------------------------------------------------------------
extern "C" void kernel_launch(void* const* d_in, const int* in_sizes, int n_in,
                              void* d_out, int out_size, void* d_ws, size_t ws_size,
                              hipStream_t stream)
{
    const float* spikes = (const float*)d_in[0];
    const float* W_emb  = (const float*)d_in[1];
    const float* b_emb  = (const float*)d_in[2];
    const float* Ws1    = (const float*)d_in[3];
    const float* bs1    = (const float*)d_in[4];
    const float* Ws2    = (const float*)d_in[5];
    const float* bs2    = (const float*)d_in[6];
    const float* Wr1    = (const float*)d_in[7];
    const float* br1    = (const float*)d_in[8];
    const float* Wr2    = (const float*)d_in[9];
    const float* br2    = (const float*)d_in[10];
    const float* Wc1    = (const float*)d_in[11];
    const float* bc1    = (const float*)d_in[12];
    const float* Wc2    = (const float*)d_in[13];
    const float* bc2    = (const float*)d_in[14];
    const int*   se     = (const int*)d_in[15];
    const int*   re     = (const int*)d_in[16];

    float* out = (float*)d_out;
    float* ws  = (float*)d_ws;

    // workspace layout (float offsets, all 16B-aligned):
    float*          P     = ws;                                   // 73,440 f
    float*          bias1 = ws + 73440;                           // 256 f
    float*          bias2 = ws + 73696;                           // 256 f
    unsigned short* wg1f  = (unsigned short*)(ws + 73952);        // 8,192 u16
    unsigned short* wg2f  = (unsigned short*)(ws + 78048);        // 32,768 u16
    unsigned short* wg3fT = (unsigned short*)(ws + 94432);        // 73,728 u16
    unsigned short* wc2f  = (unsigned short*)(ws + 131296);       // 4,608 u16
    unsigned short* h2    = (unsigned short*)(ws + 133600);       // 65536*256 u16

    const dim3 blk(256);

    (void)hipFuncSetAttribute(reinterpret_cast<const void*>(final4),
                              hipFuncAttributeMaxDynamicSharedMemorySize, LDS_B2);

    prep_kernel<<<756, blk, 0, stream>>>(
        W_emb, b_emb, Ws1, bs1, Wr1, br1, Ws2, bs2, Wr2, br2, Wc1, bc1, Wc2,
        P, bias1, bias2, wg1f, wg2f, wg3fT, wc2f);

    // h2 = relu(relu(spikes @ wg1 + bias1) @ diag(Ws2,Wr2) + bias2)
    fused12<<<1024, blk, 0, stream>>>(spikes, wg1f, bias1, wg2f, bias2, h2);

    // per-slice: transposed SR into LDS + gather + head
    final4<<<510, dim3(1024), LDS_B2, stream>>>(h2, wg3fT, P, wc2f, bc2, se, re, out);
}

// Round 9
// 74.963 us; speedup vs baseline: 7.0249x; 1.0773x over previous
//
#include <hip/hip_runtime.h>
#include <hip/hip_bf16.h>
#include <hip/hip_fp16.h>
#include <cstdint>
#include <cstddef>

typedef __attribute__((ext_vector_type(8))) short bf16x8;
typedef __attribute__((ext_vector_type(8))) _Float16 f16x8;
typedef __attribute__((ext_vector_type(4))) float f32x4;
typedef __attribute__((ext_vector_type(4))) unsigned u32x4;

__device__ inline unsigned short f2bf(float f) {   // RNE bf16
    __hip_bfloat16 h = __float2bfloat16(f);
    return __builtin_bit_cast(unsigned short, h);
}
__device__ inline unsigned short f2h(float f) {    // RNE fp16
    _Float16 h = (_Float16)f;
    return __builtin_bit_cast(unsigned short, h);
}
__device__ inline unsigned cvtpkrtz(float lo, float hi) {  // 2xf32 -> packed fp16
    unsigned pk;
    asm("v_cvt_pkrtz_f16_f32 %0, %1, %2" : "=v"(pk) : "v"(lo), "v"(hi));
    return pk;
}

// ---------------------------------------------------------------------------
// One-shot prep: P (PE@Wc1 + bc1), folded first-layer weights/biases, and all
// weights converted to MFMA fragments.
// B-frag order (wg1f/wg2f bf16, wc2f fp16): frag[f*512+l*8+j] = W[ks*32+(l>>4)*8+j][nf*16+(l&15)]
// A-frag order (wg3fT bf16, transposed): frag[((p*18+mt)*4+ks)*512+l*8+j]
//   = Wc1[p*144 + ks*32+(l>>4)*8+j][mt*16+(l&15)]
// ---------------------------------------------------------------------------
__global__ void prep_kernel(
    const float* __restrict__ W_emb, const float* __restrict__ b_emb,
    const float* __restrict__ Ws1, const float* __restrict__ bs1,
    const float* __restrict__ Wr1, const float* __restrict__ br1,
    const float* __restrict__ Ws2, const float* __restrict__ bs2,
    const float* __restrict__ Wr2, const float* __restrict__ br2,
    const float* __restrict__ Wc1, const float* __restrict__ bc1,
    const float* __restrict__ Wc2,
    float* __restrict__ P, float* __restrict__ bias1, float* __restrict__ bias2,
    unsigned short* __restrict__ wg1f, unsigned short* __restrict__ wg2f,
    unsigned short* __restrict__ wg3fT, unsigned short* __restrict__ wc2f)
{
    int id = blockIdx.x * 256 + threadIdx.x;

    if (id < 73440) {   // P[t,h] = pe[t+1]@Wc1[128:144] + pe[t]@Wc1[272:288] + bc1
        const int t = id / 288, ho = id % 288;
        float acc = bc1[ho];
#pragma unroll
        for (int i = 0; i < 8; i++) {
            const float div = expf(-1.1512925464970229f * (float)i);
            const float a1 = (float)(t + 1) * div;
            const float a0 = (float)t * div;
            acc += sinf(a1) * Wc1[(size_t)(128 + 2 * i) * 288 + ho];
            acc += cosf(a1) * Wc1[(size_t)(129 + 2 * i) * 288 + ho];
            acc += sinf(a0) * Wc1[(size_t)(272 + 2 * i) * 288 + ho];
            acc += cosf(a0) * Wc1[(size_t)(273 + 2 * i) * 288 + ho];
        }
        P[id] = acc;
        return;
    }
    id -= 73440;

    if (id < 8192) {    // wg1f: [W_emb@Ws1 | W_emb@Wr1], K padded 16->32
        const int y = id >> 12, r = id & 4095;
        const int f = r >> 9, l = (r >> 3) & 63, j = r & 7;
        const int k = ((l >> 4) << 3) + j;          // 0..31
        const int n = f * 16 + (l & 15);
        float v = 0.f;
        if (k < 16) {
            const float* Wx = y ? Wr1 : Ws1;
            for (int d = 0; d < 128; d++) v += W_emb[k * 128 + d] * Wx[d * 128 + n];
        }
        wg1f[id] = f2bf(v);
        return;
    }
    id -= 8192;

    if (id < 256) {     // bias1 = [bs1 + b_emb@Ws1 | br1 + b_emb@Wr1]
        const int y = id >> 7, c = id & 127;
        const float* Wx = y ? Wr1 : Ws1;
        float v = (y ? br1 : bs1)[c];
        for (int d = 0; d < 128; d++) v += b_emb[d] * Wx[d * 128 + c];
        bias1[id] = v;
        return;
    }
    id -= 256;

    if (id < 32768) {   // wg2f: [Ws2 | Wr2] fragments
        const int y = id >> 14, r = id & 16383;
        const int f = r >> 9, l = (r >> 3) & 63, j = r & 7;
        const int ks = f >> 3, nf = f & 7;
        const int k = ks * 32 + ((l >> 4) << 3) + j;
        const int n = nf * 16 + (l & 15);
        wg2f[id] = f2bf((y ? Wr2 : Ws2)[(size_t)k * 128 + n]);
        return;
    }
    id -= 32768;

    if (id < 256) {     // bias2 = [bs2 | br2]
        bias2[id] = (id < 128) ? bs2[id] : br2[id - 128];
        return;
    }
    id -= 256;

    if (id < 73728) {   // wg3fT: transposed A-fragments of [Wc1a | Wc1b]
        const int p = id / 36864, r = id % 36864;
        const int frag = r >> 9, l = (r >> 3) & 63, j = r & 7;
        const int mt = frag >> 2, ks = frag & 3;
        const int k = ks * 32 + ((l >> 4) << 3) + j;     // Wc1 row (K dim)
        const int n = mt * 16 + (l & 15);                // Wc1 col (output)
        wg3fT[id] = f2bf(Wc1[(size_t)(p * 144 + k) * 288 + n]);
        return;
    }
    id -= 73728;

    if (id < 4608) {    // wc2f: head weight fragments, FP16 (288x5 padded to 16)
        const int j = id & 7, l = (id >> 3) & 63, ks = id >> 9;
        const int k = ks * 32 + ((l >> 4) << 3) + j;
        const int c = l & 15;
        wc2f[id] = (c < 5) ? f2h(Wc2[(size_t)k * 5 + c]) : (unsigned short)0;
    }
}

// ---------------------------------------------------------------------------
// Kernel A: h2 = relu( relu(spikes @ wg1 + bias1) @ diag(Ws2,Wr2) + bias2 )
// 64 rows/block, 4 waves (2 row x 2 col). h1 lives in LDS.
// ---------------------------------------------------------------------------
#define H1S 264   // shorts per h1 LDS row

__global__ __launch_bounds__(256) void fused12(
    const float* __restrict__ spikes,
    const unsigned short* __restrict__ wg1f, const float* __restrict__ bias1,
    const unsigned short* __restrict__ wg2f, const float* __restrict__ bias2,
    unsigned short* __restrict__ h2)
{
    __shared__ unsigned short h1l[64 * H1S];     // 33,792 B
    const int row0 = blockIdx.x * 64;
    const int tid = threadIdx.x;
    const int w = tid >> 6, l = tid & 63;
    const int wm = w >> 1, wn = w & 1;
    const int lm = l & 15, lk = l >> 4;
    const int wrow = wm * 32;                    // local row base

    // ---- stage 0: h1 = relu(spikes @ wg1 + bias1), K=16 padded to 32 ----
    bf16x8 a0[2];
#pragma unroll
    for (int rf = 0; rf < 2; rf++) {
        bf16x8 tv = {0, 0, 0, 0, 0, 0, 0, 0};
        if (lk < 2) {
            const float* p = spikes + (size_t)(row0 + wrow + rf * 16 + lm) * 16 + lk * 8;
            const float4 v0 = *reinterpret_cast<const float4*>(p);
            const float4 v1 = *reinterpret_cast<const float4*>(p + 4);
            tv[0] = (short)f2bf(v0.x); tv[1] = (short)f2bf(v0.y);
            tv[2] = (short)f2bf(v0.z); tv[3] = (short)f2bf(v0.w);
            tv[4] = (short)f2bf(v1.x); tv[5] = (short)f2bf(v1.y);
            tv[6] = (short)f2bf(v1.z); tv[7] = (short)f2bf(v1.w);
        }
        a0[rf] = tv;
    }
    f32x4 acc[2][8];
#pragma unroll
    for (int rf = 0; rf < 2; rf++)
#pragma unroll
        for (int nf = 0; nf < 8; nf++) acc[rf][nf] = (f32x4){0.f, 0.f, 0.f, 0.f};

#pragma unroll
    for (int nf = 0; nf < 8; nf++) {
        const bf16x8 bfr = *reinterpret_cast<const bf16x8*>(
            wg1f + (size_t)(wn * 8 + nf) * 512 + l * 8);
        acc[0][nf] = __builtin_amdgcn_mfma_f32_16x16x32_bf16(a0[0], bfr, acc[0][nf], 0, 0, 0);
        acc[1][nf] = __builtin_amdgcn_mfma_f32_16x16x32_bf16(a0[1], bfr, acc[1][nf], 0, 0, 0);
    }
#pragma unroll
    for (int rf = 0; rf < 2; rf++)
#pragma unroll
        for (int nf = 0; nf < 8; nf++) {
            const int gc = wn * 128 + nf * 16 + lm;
            const float add = bias1[gc];
#pragma unroll
            for (int reg = 0; reg < 4; reg++) {
                const int r = wrow + rf * 16 + lk * 4 + reg;
                h1l[r * H1S + gc] = f2bf(fmaxf(acc[rf][nf][reg] + add, 0.f));
            }
        }
    __syncthreads();

    // ---- stage 1: h2 = relu(h1 @ diag(Ws2,Wr2) + bias2), K=128 per half ----
#pragma unroll
    for (int rf = 0; rf < 2; rf++)
#pragma unroll
        for (int nf = 0; nf < 8; nf++) acc[rf][nf] = (f32x4){0.f, 0.f, 0.f, 0.f};

#pragma unroll
    for (int ks = 0; ks < 4; ks++) {
        bf16x8 a[2];
        a[0] = *reinterpret_cast<const bf16x8*>(
            &h1l[(wrow + lm) * H1S + wn * 128 + ks * 32 + lk * 8]);
        a[1] = *reinterpret_cast<const bf16x8*>(
            &h1l[(wrow + 16 + lm) * H1S + wn * 128 + ks * 32 + lk * 8]);
#pragma unroll
        for (int nf = 0; nf < 8; nf++) {
            const bf16x8 bfr = *reinterpret_cast<const bf16x8*>(
                wg2f + (size_t)wn * 16384 + (size_t)(ks * 8 + nf) * 512 + l * 8);
            acc[0][nf] = __builtin_amdgcn_mfma_f32_16x16x32_bf16(a[0], bfr, acc[0][nf], 0, 0, 0);
            acc[1][nf] = __builtin_amdgcn_mfma_f32_16x16x32_bf16(a[1], bfr, acc[1][nf], 0, 0, 0);
        }
    }
#pragma unroll
    for (int rf = 0; rf < 2; rf++)
#pragma unroll
        for (int nf = 0; nf < 8; nf++) {
            const int gc = wn * 128 + nf * 16 + lm;
            const float add = bias2[gc];
#pragma unroll
            for (int reg = 0; reg < 4; reg++) {
                const size_t r = (size_t)(row0 + wrow + rf * 16 + lk * 4 + reg);
                h2[r * 256 + gc] = f2bf(fmaxf(acc[rf][nf][reg] + add, 0.f));
            }
        }
}

// ---------------------------------------------------------------------------
// Kernel B: per (b,t) slice.
// Phase 1 (transposed): S^T/R'^T tiles = mfma(A=Wc1^T frags, B=h2-row frags),
// epilogue packs to FP16 via v_cvt_pkrtz_f16_f32, ds_write_b64 into
// row-major LDS [128 rows][592 B] (37*16; 37 mod 8 = 5 odd -> random rows
// uniform over 8 bank groups, no xor; write/read share the linear map).
// Phase 2: per 16-edge tile, ds_read_b128 gather, h = relu(S+R) via packed
// v_pk_add_f16 + v_pk_max_f16 (2 VALU per dword), 9 MFMA 16x16x32_f16 -> out.
// ---------------------------------------------------------------------------
#define SROWB  592
#define SMATB  75776     // 128 * 592
#define LDS_B2 151552    // 2 * SMATB

__global__ __launch_bounds__(1024) void final4(
    const unsigned short* __restrict__ h2,
    const unsigned short* __restrict__ wg3fT, const float* __restrict__ Pt,
    const unsigned short* __restrict__ wc2f, const float* __restrict__ bc2,
    const int* __restrict__ se, const int* __restrict__ re,
    float* __restrict__ out)
{
    extern __shared__ unsigned char lds[];
    const int slice = blockIdx.x;                // 0..509
    const int b = slice / 255, t = slice % 255;
    const int tid = threadIdx.x, w = tid >> 6, l = tid & 63;
    const int lm = l & 15, lk = l >> 4;

    // ---- phase 1: S (p=0) and R'+P (p=1) into LDS, transposed MFMA ----
    {
        const int rowg = w & 3, colg = w >> 2;
        const int p  = colg >> 1;
        const int mtb = (colg & 1) * 9;
        const size_t hrow0 = (size_t)((b * 256 + t + 1 - p) * 128 + rowg * 32 + lm);

        bf16x8 bfr[2][4];
#pragma unroll
        for (int half = 0; half < 2; half++)
#pragma unroll
            for (int ks = 0; ks < 4; ks++)
                bfr[half][ks] = *reinterpret_cast<const bf16x8*>(
                    h2 + (hrow0 + half * 16) * 256 + p * 128 + ks * 32 + lk * 8);

        unsigned char* mb0 = lds + p * SMATB + (rowg * 32 + lm) * SROWB;
        unsigned char* mb1 = mb0 + 16 * SROWB;

#pragma unroll
        for (int m9 = 0; m9 < 9; m9++) {
            const int mt = mtb + m9;
            f32x4 acc0 = {0.f, 0.f, 0.f, 0.f};
            f32x4 acc1 = {0.f, 0.f, 0.f, 0.f};
#pragma unroll
            for (int ks = 0; ks < 4; ks++) {
                const bf16x8 afr = *reinterpret_cast<const bf16x8*>(
                    wg3fT + ((size_t)(((p * 18 + mt) << 2) + ks) << 9) + l * 8);
                acc0 = __builtin_amdgcn_mfma_f32_16x16x32_bf16(afr, bfr[0][ks], acc0, 0, 0, 0);
                acc1 = __builtin_amdgcn_mfma_f32_16x16x32_bf16(afr, bfr[1][ks], acc1, 0, 0, 0);
            }
            const int c0 = mt * 16 + lk * 4;
            float4 pa = {0.f, 0.f, 0.f, 0.f};
            if (p) pa = *reinterpret_cast<const float4*>(Pt + (size_t)t * 288 + c0);
            const int boff = mt * 32 + lk * 8;
            uint2 wv;
            wv.x = cvtpkrtz(acc0[0] + pa.x, acc0[1] + pa.y);
            wv.y = cvtpkrtz(acc0[2] + pa.z, acc0[3] + pa.w);
            *reinterpret_cast<uint2*>(mb0 + boff) = wv;
            wv.x = cvtpkrtz(acc1[0] + pa.x, acc1[1] + pa.y);
            wv.y = cvtpkrtz(acc1[2] + pa.z, acc1[3] + pa.w);
            *reinterpret_cast<uint2*>(mb1 + boff) = wv;
        }
    }

    f16x8 bfrag[9];
#pragma unroll
    for (int ks = 0; ks < 9; ks++)
        bfrag[ks] = *reinterpret_cast<const f16x8*>(wc2f + (ks * 64 + l) * 8);
    const float bias = (lm < 5) ? bc2[lm] : 0.f;

    __syncthreads();

    // ---- phase 2: gather + relu + head (4 tiles of 16 edges per wave) ----
    for (int it = 0; it < 4; it++) {
        const int e0  = (w * 4 + it) * 16;
        const int srw = se[e0 + lm];
        const int rrw = re[e0 + lm];
        const unsigned char* sb = lds + srw * SROWB + lk * 16;
        const unsigned char* rb = lds + SMATB + rrw * SROWB + lk * 16;
        f32x4 acc = {0.f, 0.f, 0.f, 0.f};
#pragma unroll
        for (int ks = 0; ks < 9; ks++) {
            const u32x4 s4 = *reinterpret_cast<const u32x4*>(sb + ks * 64);
            const u32x4 r4 = *reinterpret_cast<const u32x4*>(rb + ks * 64);
            u32x4 hw;
#pragma unroll
            for (int i = 0; i < 4; i++) {
                unsigned hsum, hrel;
                asm("v_pk_add_f16 %0, %1, %2" : "=v"(hsum) : "v"(s4[i]), "v"(r4[i]));
                asm("v_pk_max_f16 %0, %1, 0"  : "=v"(hrel) : "v"(hsum));
                hw[i] = hrel;
            }
            acc = __builtin_amdgcn_mfma_f32_16x16x32_f16(
                __builtin_bit_cast(f16x8, hw), bfrag[ks], acc, 0, 0, 0);
        }
        if (lm < 5) {
            float* op = out + ((size_t)slice * 1024 + e0 + lk * 4) * 5 + lm;
            op[0]  = acc[0] + bias;
            op[5]  = acc[1] + bias;
            op[10] = acc[2] + bias;
            op[15] = acc[3] + bias;
        }
    }
}

// ---------------------------------------------------------------------------
extern "C" void kernel_launch(void* const* d_in, const int* in_sizes, int n_in,
                              void* d_out, int out_size, void* d_ws, size_t ws_size,
                              hipStream_t stream)
{
    const float* spikes = (const float*)d_in[0];
    const float* W_emb  = (const float*)d_in[1];
    const float* b_emb  = (const float*)d_in[2];
    const float* Ws1    = (const float*)d_in[3];
    const float* bs1    = (const float*)d_in[4];
    const float* Ws2    = (const float*)d_in[5];
    const float* bs2    = (const float*)d_in[6];
    const float* Wr1    = (const float*)d_in[7];
    const float* br1    = (const float*)d_in[8];
    const float* Wr2    = (const float*)d_in[9];
    const float* br2    = (const float*)d_in[10];
    const float* Wc1    = (const float*)d_in[11];
    const float* bc1    = (const float*)d_in[12];
    const float* Wc2    = (const float*)d_in[13];
    const float* bc2    = (const float*)d_in[14];
    const int*   se     = (const int*)d_in[15];
    const int*   re     = (const int*)d_in[16];

    float* out = (float*)d_out;
    float* ws  = (float*)d_ws;

    // workspace layout (float offsets, all 16B-aligned):
    float*          P     = ws;                                   // 73,440 f
    float*          bias1 = ws + 73440;                           // 256 f
    float*          bias2 = ws + 73696;                           // 256 f
    unsigned short* wg1f  = (unsigned short*)(ws + 73952);        // 8,192 u16
    unsigned short* wg2f  = (unsigned short*)(ws + 78048);        // 32,768 u16
    unsigned short* wg3fT = (unsigned short*)(ws + 94432);        // 73,728 u16
    unsigned short* wc2f  = (unsigned short*)(ws + 131296);       // 4,608 u16
    unsigned short* h2    = (unsigned short*)(ws + 133600);       // 65536*256 u16

    const dim3 blk(256);

    (void)hipFuncSetAttribute(reinterpret_cast<const void*>(final4),
                              hipFuncAttributeMaxDynamicSharedMemorySize, LDS_B2);

    prep_kernel<<<756, blk, 0, stream>>>(
        W_emb, b_emb, Ws1, bs1, Wr1, br1, Ws2, bs2, Wr2, br2, Wc1, bc1, Wc2,
        P, bias1, bias2, wg1f, wg2f, wg3fT, wc2f);

    // h2 = relu(relu(spikes @ wg1 + bias1) @ diag(Ws2,Wr2) + bias2)
    fused12<<<1024, blk, 0, stream>>>(spikes, wg1f, bias1, wg2f, bias2, h2);

    // per-slice: transposed SR into LDS (fp16) + gather + head
    final4<<<510, dim3(1024), LDS_B2, stream>>>(h2, wg3fT, P, wc2f, bc2, se, re, out);
}

// Round 10
// 56.516 us; speedup vs baseline: 9.3179x; 1.3264x over previous
//
#include <hip/hip_runtime.h>
#include <hip/hip_bf16.h>
#include <hip/hip_fp16.h>
#include <cstdint>
#include <cstddef>

typedef __attribute__((ext_vector_type(8))) short bf16x8;
typedef __attribute__((ext_vector_type(8))) _Float16 f16x8;
typedef __attribute__((ext_vector_type(4))) float f32x4;
typedef __attribute__((ext_vector_type(4))) unsigned u32x4;

__device__ inline unsigned short f2bf(float f) {   // RNE bf16
    __hip_bfloat16 h = __float2bfloat16(f);
    return __builtin_bit_cast(unsigned short, h);
}
__device__ inline unsigned short f2h(float f) {    // RNE fp16
    _Float16 h = (_Float16)f;
    return __builtin_bit_cast(unsigned short, h);
}
__device__ inline unsigned cvtpkrtz(float lo, float hi) {  // 2xf32 -> packed fp16
    unsigned pk;
    asm("v_cvt_pkrtz_f16_f32 %0, %1, %2" : "=v"(pk) : "v"(lo), "v"(hi));
    return pk;
}

// ---------------------------------------------------------------------------
// One-shot prep: P (PE@Wc1 + bc1), folded first-layer weights/biases, and all
// weights converted to MFMA fragments.
// B-frag order (wg1f/wg2f bf16, wc2f fp16): frag[f*512+l*8+j] = W[ks*32+(l>>4)*8+j][nf*16+(l&15)]
// A-frag order (wg3fT bf16, transposed): frag[((p*18+mt)*4+ks)*512+l*8+j]
//   = Wc1[p*144 + ks*32+(l>>4)*8+j][mt*16+(l&15)]
// ---------------------------------------------------------------------------
__global__ void prep_kernel(
    const float* __restrict__ W_emb, const float* __restrict__ b_emb,
    const float* __restrict__ Ws1, const float* __restrict__ bs1,
    const float* __restrict__ Wr1, const float* __restrict__ br1,
    const float* __restrict__ Ws2, const float* __restrict__ bs2,
    const float* __restrict__ Wr2, const float* __restrict__ br2,
    const float* __restrict__ Wc1, const float* __restrict__ bc1,
    const float* __restrict__ Wc2,
    float* __restrict__ P, float* __restrict__ bias1, float* __restrict__ bias2,
    unsigned short* __restrict__ wg1f, unsigned short* __restrict__ wg2f,
    unsigned short* __restrict__ wg3fT, unsigned short* __restrict__ wc2f)
{
    int id = blockIdx.x * 256 + threadIdx.x;

    if (id < 73440) {   // P[t,h] = pe[t+1]@Wc1[128:144] + pe[t]@Wc1[272:288] + bc1
        const int t = id / 288, ho = id % 288;
        float acc = bc1[ho];
#pragma unroll
        for (int i = 0; i < 8; i++) {
            const float div = expf(-1.1512925464970229f * (float)i);
            const float a1 = (float)(t + 1) * div;
            const float a0 = (float)t * div;
            acc += sinf(a1) * Wc1[(size_t)(128 + 2 * i) * 288 + ho];
            acc += cosf(a1) * Wc1[(size_t)(129 + 2 * i) * 288 + ho];
            acc += sinf(a0) * Wc1[(size_t)(272 + 2 * i) * 288 + ho];
            acc += cosf(a0) * Wc1[(size_t)(273 + 2 * i) * 288 + ho];
        }
        P[id] = acc;
        return;
    }
    id -= 73440;

    if (id < 8192) {    // wg1f: [W_emb@Ws1 | W_emb@Wr1], K padded 16->32
        const int y = id >> 12, r = id & 4095;
        const int f = r >> 9, l = (r >> 3) & 63, j = r & 7;
        const int k = ((l >> 4) << 3) + j;          // 0..31
        const int n = f * 16 + (l & 15);
        float v = 0.f;
        if (k < 16) {
            const float* Wx = y ? Wr1 : Ws1;
            for (int d = 0; d < 128; d++) v += W_emb[k * 128 + d] * Wx[d * 128 + n];
        }
        wg1f[id] = f2bf(v);
        return;
    }
    id -= 8192;

    if (id < 256) {     // bias1 = [bs1 + b_emb@Ws1 | br1 + b_emb@Wr1]
        const int y = id >> 7, c = id & 127;
        const float* Wx = y ? Wr1 : Ws1;
        float v = (y ? br1 : bs1)[c];
        for (int d = 0; d < 128; d++) v += b_emb[d] * Wx[d * 128 + c];
        bias1[id] = v;
        return;
    }
    id -= 256;

    if (id < 32768) {   // wg2f: [Ws2 | Wr2] fragments
        const int y = id >> 14, r = id & 16383;
        const int f = r >> 9, l = (r >> 3) & 63, j = r & 7;
        const int ks = f >> 3, nf = f & 7;
        const int k = ks * 32 + ((l >> 4) << 3) + j;
        const int n = nf * 16 + (l & 15);
        wg2f[id] = f2bf((y ? Wr2 : Ws2)[(size_t)k * 128 + n]);
        return;
    }
    id -= 32768;

    if (id < 256) {     // bias2 = [bs2 | br2]
        bias2[id] = (id < 128) ? bs2[id] : br2[id - 128];
        return;
    }
    id -= 256;

    if (id < 73728) {   // wg3fT: transposed A-fragments of [Wc1a | Wc1b]
        const int p = id / 36864, r = id % 36864;
        const int frag = r >> 9, l = (r >> 3) & 63, j = r & 7;
        const int mt = frag >> 2, ks = frag & 3;
        const int k = ks * 32 + ((l >> 4) << 3) + j;     // Wc1 row (K dim)
        const int n = mt * 16 + (l & 15);                // Wc1 col (output)
        wg3fT[id] = f2bf(Wc1[(size_t)(p * 144 + k) * 288 + n]);
        return;
    }
    id -= 73728;

    if (id < 4608) {    // wc2f: head weight fragments, FP16 (288x5 padded to 16)
        const int j = id & 7, l = (id >> 3) & 63, ks = id >> 9;
        const int k = ks * 32 + ((l >> 4) << 3) + j;
        const int c = l & 15;
        wc2f[id] = (c < 5) ? f2h(Wc2[(size_t)k * 5 + c]) : (unsigned short)0;
    }
}

// ---------------------------------------------------------------------------
// Mega-fused per-(b,t)-slice kernel, 16 waves (1024 thr):
// Phase A: h1[y][node] = relu(spikes(b, tt_y, node) @ wg1[y] + bias1[y]),
//   tt_0 = t+1 (send chain), tt_1 = t (recv chain). -> LDS (272 B row stride;
//   17x16B, odd -> per-row bank rotation, 2-way max on b128 reads = free).
// Phase B: h2[y] = relu(h1[y] @ wg2[y] + bias2[y]) -> LDS (same layout).
// Phase C-load: each wave pulls its 32 h2 rows as MFMA B-frags into regs.
// Phase C: S^T/R'^T = mfma(Wc1^T A-frags, h2 B-frags) -> packed fp16
//   (v_cvt_pkrtz) -> LDS [p][128 rows][592 B] (37x16, odd -> uniform bank
//   spread for random gathered rows), overwriting h1/h2.
// Phase D: per 16-edge tile: ds_read_b128 gather, h = relu(S+R) via
//   v_pk_add_f16/v_pk_max_f16, 9 x mfma_f32_16x16x32_f16 -> out.
// h2 never touches HBM; zero duplication (send(t+1)/recv(t) partition).
// ---------------------------------------------------------------------------
#define H1ROWB 272       // h1/h2 LDS row stride (17*16)
#define H1YB   34816     // 128 * 272 per y-half
#define H2BASE 69632     // h2 region base (2 * H1YB)
#define SROWB  592
#define SMATB  75776     // 128 * 592
#define LDS_B2 151552    // 2 * SMATB  (phases A/B live in [0,139264))

__global__ __launch_bounds__(1024) void final5(
    const float* __restrict__ spikes,
    const unsigned short* __restrict__ wg1f, const float* __restrict__ bias1,
    const unsigned short* __restrict__ wg2f, const float* __restrict__ bias2,
    const unsigned short* __restrict__ wg3fT, const float* __restrict__ Pt,
    const unsigned short* __restrict__ wc2f, const float* __restrict__ bc2,
    const int* __restrict__ se, const int* __restrict__ re,
    float* __restrict__ out)
{
    extern __shared__ unsigned char lds[];
    const int slice = blockIdx.x;                // 0..509
    const int b = slice / 255, t = slice % 255;
    const int tid = threadIdx.x, w = tid >> 6, l = tid & 63;
    const int lm = l & 15, lk = l >> 4;

    // ---- phase A: h1 (both chains) into LDS ----
    {
        const int y = w >> 3, rowblk = w & 7;    // y: 0=send(t+1), 1=recv(t)
        const int tt = y ? t : t + 1;
        bf16x8 a0 = {0, 0, 0, 0, 0, 0, 0, 0};
        if (lk < 2) {
            const float* p = spikes +
                ((size_t)((b * 256 + tt) * 128 + rowblk * 16 + lm)) * 16 + lk * 8;
            const float4 v0 = *reinterpret_cast<const float4*>(p);
            const float4 v1 = *reinterpret_cast<const float4*>(p + 4);
            a0[0] = (short)f2bf(v0.x); a0[1] = (short)f2bf(v0.y);
            a0[2] = (short)f2bf(v0.z); a0[3] = (short)f2bf(v0.w);
            a0[4] = (short)f2bf(v1.x); a0[5] = (short)f2bf(v1.y);
            a0[6] = (short)f2bf(v1.z); a0[7] = (short)f2bf(v1.w);
        }
        f32x4 acc[8];
#pragma unroll
        for (int nf = 0; nf < 8; nf++) acc[nf] = (f32x4){0.f, 0.f, 0.f, 0.f};
#pragma unroll
        for (int nf = 0; nf < 8; nf++) {
            const bf16x8 bfr = *reinterpret_cast<const bf16x8*>(
                wg1f + y * 4096 + nf * 512 + l * 8);
            acc[nf] = __builtin_amdgcn_mfma_f32_16x16x32_bf16(a0, bfr, acc[nf], 0, 0, 0);
        }
        unsigned char* hb = lds + y * H1YB + (rowblk * 16 + lk * 4) * H1ROWB;
#pragma unroll
        for (int nf = 0; nf < 8; nf++) {
            const int c = nf * 16 + lm;
            const float add = bias1[y * 128 + c];
#pragma unroll
            for (int reg = 0; reg < 4; reg++)
                *reinterpret_cast<unsigned short*>(hb + reg * H1ROWB + c * 2) =
                    f2bf(fmaxf(acc[nf][reg] + add, 0.f));
        }
    }
    __syncthreads();

    // ---- phase B: h2 (both chains) into LDS ----
    {
        const int y = w >> 3, rowblk = w & 7;
        bf16x8 a[4];
#pragma unroll
        for (int ks = 0; ks < 4; ks++)
            a[ks] = *reinterpret_cast<const bf16x8*>(
                lds + y * H1YB + (rowblk * 16 + lm) * H1ROWB + ks * 64 + lk * 16);
        f32x4 acc[8];
#pragma unroll
        for (int nf = 0; nf < 8; nf++) acc[nf] = (f32x4){0.f, 0.f, 0.f, 0.f};
#pragma unroll
        for (int ks = 0; ks < 4; ks++)
#pragma unroll
            for (int nf = 0; nf < 8; nf++) {
                const bf16x8 bfr = *reinterpret_cast<const bf16x8*>(
                    wg2f + (size_t)y * 16384 + (size_t)(ks * 8 + nf) * 512 + l * 8);
                acc[nf] = __builtin_amdgcn_mfma_f32_16x16x32_bf16(a[ks], bfr, acc[nf], 0, 0, 0);
            }
        unsigned char* hb = lds + H2BASE + y * H1YB + (rowblk * 16 + lk * 4) * H1ROWB;
#pragma unroll
        for (int nf = 0; nf < 8; nf++) {
            const int c = nf * 16 + lm;
            const float add = bias2[y * 128 + c];
#pragma unroll
            for (int reg = 0; reg < 4; reg++)
                *reinterpret_cast<unsigned short*>(hb + reg * H1ROWB + c * 2) =
                    f2bf(fmaxf(acc[nf][reg] + add, 0.f));
        }
    }
    __syncthreads();

    // ---- phase C-load: h2 B-frags -> registers; head frags ----
    const int rowg = w & 3, colg = w >> 2;
    const int p  = colg >> 1;                    // 0 = S(send), 1 = R(recv)
    const int mtb = (colg & 1) * 9;
    bf16x8 bfr[2][4];
#pragma unroll
    for (int half = 0; half < 2; half++)
#pragma unroll
        for (int ks = 0; ks < 4; ks++)
            bfr[half][ks] = *reinterpret_cast<const bf16x8*>(
                lds + H2BASE + p * H1YB +
                (rowg * 32 + half * 16 + lm) * H1ROWB + ks * 64 + lk * 16);
    f16x8 bfrag[9];
#pragma unroll
    for (int ks = 0; ks < 9; ks++)
        bfrag[ks] = *reinterpret_cast<const f16x8*>(wc2f + (ks * 64 + l) * 8);
    const float bias = (lm < 5) ? bc2[lm] : 0.f;
    __syncthreads();

    // ---- phase C: S/R tiles -> LDS (fp16, overwrites h1/h2) ----
    {
        unsigned char* mb0 = lds + p * SMATB + (rowg * 32 + lm) * SROWB;
        unsigned char* mb1 = mb0 + 16 * SROWB;
#pragma unroll
        for (int m9 = 0; m9 < 9; m9++) {
            const int mt = mtb + m9;
            f32x4 acc0 = {0.f, 0.f, 0.f, 0.f};
            f32x4 acc1 = {0.f, 0.f, 0.f, 0.f};
#pragma unroll
            for (int ks = 0; ks < 4; ks++) {
                const bf16x8 afr = *reinterpret_cast<const bf16x8*>(
                    wg3fT + ((size_t)(((p * 18 + mt) << 2) + ks) << 9) + l * 8);
                acc0 = __builtin_amdgcn_mfma_f32_16x16x32_bf16(afr, bfr[0][ks], acc0, 0, 0, 0);
                acc1 = __builtin_amdgcn_mfma_f32_16x16x32_bf16(afr, bfr[1][ks], acc1, 0, 0, 0);
            }
            const int c0 = mt * 16 + lk * 4;
            float4 pa = {0.f, 0.f, 0.f, 0.f};
            if (p) pa = *reinterpret_cast<const float4*>(Pt + (size_t)t * 288 + c0);
            const int boff = mt * 32 + lk * 8;
            uint2 wv;
            wv.x = cvtpkrtz(acc0[0] + pa.x, acc0[1] + pa.y);
            wv.y = cvtpkrtz(acc0[2] + pa.z, acc0[3] + pa.w);
            *reinterpret_cast<uint2*>(mb0 + boff) = wv;
            wv.x = cvtpkrtz(acc1[0] + pa.x, acc1[1] + pa.y);
            wv.y = cvtpkrtz(acc1[2] + pa.z, acc1[3] + pa.w);
            *reinterpret_cast<uint2*>(mb1 + boff) = wv;
        }
    }
    __syncthreads();

    // ---- phase D: gather + relu + head (4 tiles of 16 edges per wave) ----
    for (int it = 0; it < 4; it++) {
        const int e0  = (w * 4 + it) * 16;
        const int srw = se[e0 + lm];
        const int rrw = re[e0 + lm];
        const unsigned char* sb = lds + srw * SROWB + lk * 16;
        const unsigned char* rb = lds + SMATB + rrw * SROWB + lk * 16;
        f32x4 acc = {0.f, 0.f, 0.f, 0.f};
#pragma unroll
        for (int ks = 0; ks < 9; ks++) {
            const u32x4 s4 = *reinterpret_cast<const u32x4*>(sb + ks * 64);
            const u32x4 r4 = *reinterpret_cast<const u32x4*>(rb + ks * 64);
            u32x4 hw;
#pragma unroll
            for (int i = 0; i < 4; i++) {
                unsigned hsum, hrel;
                asm("v_pk_add_f16 %0, %1, %2" : "=v"(hsum) : "v"(s4[i]), "v"(r4[i]));
                asm("v_pk_max_f16 %0, %1, 0"  : "=v"(hrel) : "v"(hsum));
                hw[i] = hrel;
            }
            acc = __builtin_amdgcn_mfma_f32_16x16x32_f16(
                __builtin_bit_cast(f16x8, hw), bfrag[ks], acc, 0, 0, 0);
        }
        if (lm < 5) {
            float* op = out + ((size_t)slice * 1024 + e0 + lk * 4) * 5 + lm;
            op[0]  = acc[0] + bias;
            op[5]  = acc[1] + bias;
            op[10] = acc[2] + bias;
            op[15] = acc[3] + bias;
        }
    }
}

// ---------------------------------------------------------------------------
extern "C" void kernel_launch(void* const* d_in, const int* in_sizes, int n_in,
                              void* d_out, int out_size, void* d_ws, size_t ws_size,
                              hipStream_t stream)
{
    const float* spikes = (const float*)d_in[0];
    const float* W_emb  = (const float*)d_in[1];
    const float* b_emb  = (const float*)d_in[2];
    const float* Ws1    = (const float*)d_in[3];
    const float* bs1    = (const float*)d_in[4];
    const float* Ws2    = (const float*)d_in[5];
    const float* bs2    = (const float*)d_in[6];
    const float* Wr1    = (const float*)d_in[7];
    const float* br1    = (const float*)d_in[8];
    const float* Wr2    = (const float*)d_in[9];
    const float* br2    = (const float*)d_in[10];
    const float* Wc1    = (const float*)d_in[11];
    const float* bc1    = (const float*)d_in[12];
    const float* Wc2    = (const float*)d_in[13];
    const float* bc2    = (const float*)d_in[14];
    const int*   se     = (const int*)d_in[15];
    const int*   re     = (const int*)d_in[16];

    float* out = (float*)d_out;
    float* ws  = (float*)d_ws;

    // workspace layout (float offsets, all 16B-aligned):
    float*          P     = ws;                                   // 73,440 f
    float*          bias1 = ws + 73440;                           // 256 f
    float*          bias2 = ws + 73696;                           // 256 f
    unsigned short* wg1f  = (unsigned short*)(ws + 73952);        // 8,192 u16
    unsigned short* wg2f  = (unsigned short*)(ws + 78048);        // 32,768 u16
    unsigned short* wg3fT = (unsigned short*)(ws + 94432);        // 73,728 u16
    unsigned short* wc2f  = (unsigned short*)(ws + 131296);       // 4,608 u16

    const dim3 blk(256);

    (void)hipFuncSetAttribute(reinterpret_cast<const void*>(final5),
                              hipFuncAttributeMaxDynamicSharedMemorySize, LDS_B2);

    prep_kernel<<<756, blk, 0, stream>>>(
        W_emb, b_emb, Ws1, bs1, Wr1, br1, Ws2, bs2, Wr2, br2, Wc1, bc1, Wc2,
        P, bias1, bias2, wg1f, wg2f, wg3fT, wc2f);

    // everything else fused per slice: h1 -> h2 -> S/R -> gather -> head
    final5<<<510, dim3(1024), LDS_B2, stream>>>(
        spikes, wg1f, bias1, wg2f, bias2, wg3fT, P, wc2f, bc2, se, re, out);
}

// Round 11
// 51.481 us; speedup vs baseline: 10.2292x; 1.0978x over previous
//
#include <hip/hip_runtime.h>
#include <hip/hip_bf16.h>
#include <hip/hip_fp16.h>
#include <cstdint>
#include <cstddef>

typedef __attribute__((ext_vector_type(8))) short bf16x8;
typedef __attribute__((ext_vector_type(8))) _Float16 f16x8;
typedef __attribute__((ext_vector_type(4))) float f32x4;
typedef __attribute__((ext_vector_type(4))) unsigned u32x4;

__device__ inline unsigned short f2bf(float f) {   // RNE bf16
    __hip_bfloat16 h = __float2bfloat16(f);
    return __builtin_bit_cast(unsigned short, h);
}
__device__ inline unsigned short f2h(float f) {    // RNE fp16
    _Float16 h = (_Float16)f;
    return __builtin_bit_cast(unsigned short, h);
}
__device__ inline unsigned cvtpkrtz(float lo, float hi) {  // 2xf32 -> packed fp16
    unsigned pk;
    asm("v_cvt_pkrtz_f16_f32 %0, %1, %2" : "=v"(pk) : "v"(lo), "v"(hi));
    return pk;
}

// ---------------------------------------------------------------------------
// One-shot prep. Blocks 0..286: P[t,h] = pe[t+1]@Wc1[128:144] + pe[t]@Wc1
// [272:288] + bc1, with the <=48 distinct (sin,cos) pairs per block computed
// once into LDS (32 FMA/thread instead of 64 trig/thread).
// Blocks 287..: weight fragments (same carve order as before).
// B-frag order (wg1f/wg2f bf16, wc2f fp16): frag[f*512+l*8+j] = W[ks*32+(l>>4)*8+j][nf*16+(l&15)]
// A-frag order (wg3fT bf16, transposed): frag[((p*18+mt)*4+ks)*512+l*8+j]
//   = Wc1[p*144 + ks*32+(l>>4)*8+j][mt*16+(l&15)]
// ---------------------------------------------------------------------------
__global__ void prep_kernel(
    const float* __restrict__ W_emb, const float* __restrict__ b_emb,
    const float* __restrict__ Ws1, const float* __restrict__ bs1,
    const float* __restrict__ Wr1, const float* __restrict__ br1,
    const float* __restrict__ Ws2, const float* __restrict__ bs2,
    const float* __restrict__ Wr2, const float* __restrict__ br2,
    const float* __restrict__ Wc1, const float* __restrict__ bc1,
    const float* __restrict__ Wc2,
    float* __restrict__ P, float* __restrict__ bias1, float* __restrict__ bias2,
    unsigned short* __restrict__ wg1f, unsigned short* __restrict__ wg2f,
    unsigned short* __restrict__ wg3fT, unsigned short* __restrict__ wc2f)
{
    const int tid = threadIdx.x;

    if (blockIdx.x < 287) {            // ---- P section (ids 0..73439) ----
        __shared__ float sv[3][16], cv[3][16];
        const int base = blockIdx.x * 256;
        const int t0 = base / 288;
        if (tid < 48) {
            const int dt = tid >> 4, i = tid & 15;   // i indexes pe pair (0..15 -> 2 halves)
            // div for pe index pair i: exponents use i/2 of 0..7 on even/odd
            const int ii = i >> 1;                   // 0..7
            const float div = expf(-1.1512925464970229f * (float)ii);
            const float ang = (float)(t0 + dt) * div;
            sv[dt][i] = sinf(ang);                   // note: only ii matters; duplicated
            cv[dt][i] = cosf(ang);
        }
        __syncthreads();
        const int id = base + tid;
        if (id < 73440) {
            const int t = id / 288, ho = id % 288;
            const int dt = t - t0;                   // 0 or 1
            float acc = bc1[ho];
#pragma unroll
            for (int i = 0; i < 8; i++) {
                acc += sv[dt + 1][2 * i] * Wc1[(size_t)(128 + 2 * i) * 288 + ho];
                acc += cv[dt + 1][2 * i] * Wc1[(size_t)(129 + 2 * i) * 288 + ho];
                acc += sv[dt][2 * i]     * Wc1[(size_t)(272 + 2 * i) * 288 + ho];
                acc += cv[dt][2 * i]     * Wc1[(size_t)(273 + 2 * i) * 288 + ho];
            }
            P[id] = acc;
        }
        return;
    }

    int id = (blockIdx.x - 287) * 256 + tid;

    if (id < 8192) {    // wg1f: [W_emb@Ws1 | W_emb@Wr1], K padded 16->32
        const int y = id >> 12, r = id & 4095;
        const int f = r >> 9, l = (r >> 3) & 63, j = r & 7;
        const int k = ((l >> 4) << 3) + j;          // 0..31
        const int n = f * 16 + (l & 15);
        float v = 0.f;
        if (k < 16) {
            const float* Wx = y ? Wr1 : Ws1;
            for (int d = 0; d < 128; d++) v += W_emb[k * 128 + d] * Wx[d * 128 + n];
        }
        wg1f[id] = f2bf(v);
        return;
    }
    id -= 8192;

    if (id < 256) {     // bias1 = [bs1 + b_emb@Ws1 | br1 + b_emb@Wr1]
        const int y = id >> 7, c = id & 127;
        const float* Wx = y ? Wr1 : Ws1;
        float v = (y ? br1 : bs1)[c];
        for (int d = 0; d < 128; d++) v += b_emb[d] * Wx[d * 128 + c];
        bias1[id] = v;
        return;
    }
    id -= 256;

    if (id < 32768) {   // wg2f: [Ws2 | Wr2] fragments
        const int y = id >> 14, r = id & 16383;
        const int f = r >> 9, l = (r >> 3) & 63, j = r & 7;
        const int ks = f >> 3, nf = f & 7;
        const int k = ks * 32 + ((l >> 4) << 3) + j;
        const int n = nf * 16 + (l & 15);
        wg2f[id] = f2bf((y ? Wr2 : Ws2)[(size_t)k * 128 + n]);
        return;
    }
    id -= 32768;

    if (id < 256) {     // bias2 = [bs2 | br2]
        bias2[id] = (id < 128) ? bs2[id] : br2[id - 128];
        return;
    }
    id -= 256;

    if (id < 73728) {   // wg3fT: transposed A-fragments of [Wc1a | Wc1b]
        const int p = id / 36864, r = id % 36864;
        const int frag = r >> 9, l = (r >> 3) & 63, j = r & 7;
        const int mt = frag >> 2, ks = frag & 3;
        const int k = ks * 32 + ((l >> 4) << 3) + j;     // Wc1 row (K dim)
        const int n = mt * 16 + (l & 15);                // Wc1 col (output)
        wg3fT[id] = f2bf(Wc1[(size_t)(p * 144 + k) * 288 + n]);
        return;
    }
    id -= 73728;

    if (id < 4608) {    // wc2f: head weight fragments, FP16 (288x5 padded to 16)
        const int j = id & 7, l = (id >> 3) & 63, ks = id >> 9;
        const int k = ks * 32 + ((l >> 4) << 3) + j;
        const int c = l & 15;
        wc2f[id] = (c < 5) ? f2h(Wc2[(size_t)k * 5 + c]) : (unsigned short)0;
    }
}

// ---------------------------------------------------------------------------
// Mega-fused per-(b,t)-slice kernel, 16 waves (1024 thr):
// A: h1 -> LDS; B: h2 -> LDS; C-load: h2 B-frags -> regs; C: S^T/R'^T
// (fp16, cvt_pkrtz) -> LDS [p][128][592]; D: 4-way-ILP gather + packed
// relu + 9 x mfma_f32_16x16x32_f16 -> out.  h2 never touches HBM.
// ---------------------------------------------------------------------------
#define H1ROWB 272       // h1/h2 LDS row stride (17*16)
#define H1YB   34816     // 128 * 272 per y-half
#define H2BASE 69632     // h2 region base (2 * H1YB)
#define SROWB  592
#define SMATB  75776     // 128 * 592
#define LDS_B2 151552    // 2 * SMATB  (phases A/B live in [0,139264))

__global__ __launch_bounds__(1024) void final5(
    const float* __restrict__ spikes,
    const unsigned short* __restrict__ wg1f, const float* __restrict__ bias1,
    const unsigned short* __restrict__ wg2f, const float* __restrict__ bias2,
    const unsigned short* __restrict__ wg3fT, const float* __restrict__ Pt,
    const unsigned short* __restrict__ wc2f, const float* __restrict__ bc2,
    const int* __restrict__ se, const int* __restrict__ re,
    float* __restrict__ out)
{
    extern __shared__ unsigned char lds[];
    const int slice = blockIdx.x;                // 0..509
    const int b = slice / 255, t = slice % 255;
    const int tid = threadIdx.x, w = tid >> 6, l = tid & 63;
    const int lm = l & 15, lk = l >> 4;

    // ---- phase A: h1 (both chains) into LDS ----
    {
        const int y = w >> 3, rowblk = w & 7;    // y: 0=send(t+1), 1=recv(t)
        const int tt = y ? t : t + 1;
        bf16x8 a0 = {0, 0, 0, 0, 0, 0, 0, 0};
        if (lk < 2) {
            const float* p = spikes +
                ((size_t)((b * 256 + tt) * 128 + rowblk * 16 + lm)) * 16 + lk * 8;
            const float4 v0 = *reinterpret_cast<const float4*>(p);
            const float4 v1 = *reinterpret_cast<const float4*>(p + 4);
            a0[0] = (short)f2bf(v0.x); a0[1] = (short)f2bf(v0.y);
            a0[2] = (short)f2bf(v0.z); a0[3] = (short)f2bf(v0.w);
            a0[4] = (short)f2bf(v1.x); a0[5] = (short)f2bf(v1.y);
            a0[6] = (short)f2bf(v1.z); a0[7] = (short)f2bf(v1.w);
        }
        f32x4 acc[8];
#pragma unroll
        for (int nf = 0; nf < 8; nf++) acc[nf] = (f32x4){0.f, 0.f, 0.f, 0.f};
#pragma unroll
        for (int nf = 0; nf < 8; nf++) {
            const bf16x8 bfr = *reinterpret_cast<const bf16x8*>(
                wg1f + y * 4096 + nf * 512 + l * 8);
            acc[nf] = __builtin_amdgcn_mfma_f32_16x16x32_bf16(a0, bfr, acc[nf], 0, 0, 0);
        }
        unsigned char* hb = lds + y * H1YB + (rowblk * 16 + lk * 4) * H1ROWB;
#pragma unroll
        for (int nf = 0; nf < 8; nf++) {
            const int c = nf * 16 + lm;
            const float add = bias1[y * 128 + c];
#pragma unroll
            for (int reg = 0; reg < 4; reg++)
                *reinterpret_cast<unsigned short*>(hb + reg * H1ROWB + c * 2) =
                    f2bf(fmaxf(acc[nf][reg] + add, 0.f));
        }
    }
    __syncthreads();

    // ---- phase B: h2 (both chains) into LDS ----
    {
        const int y = w >> 3, rowblk = w & 7;
        bf16x8 a[4];
#pragma unroll
        for (int ks = 0; ks < 4; ks++)
            a[ks] = *reinterpret_cast<const bf16x8*>(
                lds + y * H1YB + (rowblk * 16 + lm) * H1ROWB + ks * 64 + lk * 16);
        f32x4 acc[8];
#pragma unroll
        for (int nf = 0; nf < 8; nf++) acc[nf] = (f32x4){0.f, 0.f, 0.f, 0.f};
#pragma unroll
        for (int ks = 0; ks < 4; ks++)
#pragma unroll
            for (int nf = 0; nf < 8; nf++) {
                const bf16x8 bfr = *reinterpret_cast<const bf16x8*>(
                    wg2f + (size_t)y * 16384 + (size_t)(ks * 8 + nf) * 512 + l * 8);
                acc[nf] = __builtin_amdgcn_mfma_f32_16x16x32_bf16(a[ks], bfr, acc[nf], 0, 0, 0);
            }
        unsigned char* hb = lds + H2BASE + y * H1YB + (rowblk * 16 + lk * 4) * H1ROWB;
#pragma unroll
        for (int nf = 0; nf < 8; nf++) {
            const int c = nf * 16 + lm;
            const float add = bias2[y * 128 + c];
#pragma unroll
            for (int reg = 0; reg < 4; reg++)
                *reinterpret_cast<unsigned short*>(hb + reg * H1ROWB + c * 2) =
                    f2bf(fmaxf(acc[nf][reg] + add, 0.f));
        }
    }
    __syncthreads();

    // ---- phase C-load: h2 B-frags -> registers; head frags ----
    const int rowg = w & 3, colg = w >> 2;
    const int p  = colg >> 1;                    // 0 = S(send), 1 = R(recv)
    const int mtb = (colg & 1) * 9;
    bf16x8 bfr[2][4];
#pragma unroll
    for (int half = 0; half < 2; half++)
#pragma unroll
        for (int ks = 0; ks < 4; ks++)
            bfr[half][ks] = *reinterpret_cast<const bf16x8*>(
                lds + H2BASE + p * H1YB +
                (rowg * 32 + half * 16 + lm) * H1ROWB + ks * 64 + lk * 16);
    f16x8 bfrag[9];
#pragma unroll
    for (int ks = 0; ks < 9; ks++)
        bfrag[ks] = *reinterpret_cast<const f16x8*>(wc2f + (ks * 64 + l) * 8);
    const float bias = (lm < 5) ? bc2[lm] : 0.f;
    __syncthreads();

    // ---- phase C: S/R tiles -> LDS (fp16, overwrites h1/h2) ----
    {
        unsigned char* mb0 = lds + p * SMATB + (rowg * 32 + lm) * SROWB;
        unsigned char* mb1 = mb0 + 16 * SROWB;
#pragma unroll
        for (int m9 = 0; m9 < 9; m9++) {
            const int mt = mtb + m9;
            f32x4 acc0 = {0.f, 0.f, 0.f, 0.f};
            f32x4 acc1 = {0.f, 0.f, 0.f, 0.f};
#pragma unroll
            for (int ks = 0; ks < 4; ks++) {
                const bf16x8 afr = *reinterpret_cast<const bf16x8*>(
                    wg3fT + ((size_t)(((p * 18 + mt) << 2) + ks) << 9) + l * 8);
                acc0 = __builtin_amdgcn_mfma_f32_16x16x32_bf16(afr, bfr[0][ks], acc0, 0, 0, 0);
                acc1 = __builtin_amdgcn_mfma_f32_16x16x32_bf16(afr, bfr[1][ks], acc1, 0, 0, 0);
            }
            const int c0 = mt * 16 + lk * 4;
            float4 pa = {0.f, 0.f, 0.f, 0.f};
            if (p) pa = *reinterpret_cast<const float4*>(Pt + (size_t)t * 288 + c0);
            const int boff = mt * 32 + lk * 8;
            uint2 wv;
            wv.x = cvtpkrtz(acc0[0] + pa.x, acc0[1] + pa.y);
            wv.y = cvtpkrtz(acc0[2] + pa.z, acc0[3] + pa.w);
            *reinterpret_cast<uint2*>(mb0 + boff) = wv;
            wv.x = cvtpkrtz(acc1[0] + pa.x, acc1[1] + pa.y);
            wv.y = cvtpkrtz(acc1[2] + pa.z, acc1[3] + pa.w);
            *reinterpret_cast<uint2*>(mb1 + boff) = wv;
        }
    }
    __syncthreads();

    // ---- phase D: 4-way-ILP gather + relu + head ----
    {
        const unsigned char* sb[4];
        const unsigned char* rb[4];
#pragma unroll
        for (int it = 0; it < 4; it++) {
            const int e0 = (w * 4 + it) * 16;
            sb[it] = lds + se[e0 + lm] * SROWB + lk * 16;
            rb[it] = lds + SMATB + re[e0 + lm] * SROWB + lk * 16;
        }
        f32x4 acc[4];
#pragma unroll
        for (int it = 0; it < 4; it++) acc[it] = (f32x4){0.f, 0.f, 0.f, 0.f};

#pragma unroll
        for (int ks = 0; ks < 9; ks++) {
            u32x4 s4[4], r4[4];
#pragma unroll
            for (int it = 0; it < 4; it++) {
                s4[it] = *reinterpret_cast<const u32x4*>(sb[it] + ks * 64);
                r4[it] = *reinterpret_cast<const u32x4*>(rb[it] + ks * 64);
            }
#pragma unroll
            for (int it = 0; it < 4; it++) {
                u32x4 hw;
#pragma unroll
                for (int i = 0; i < 4; i++) {
                    unsigned hsum, hrel;
                    asm("v_pk_add_f16 %0, %1, %2" : "=v"(hsum) : "v"(s4[it][i]), "v"(r4[it][i]));
                    asm("v_pk_max_f16 %0, %1, 0"  : "=v"(hrel) : "v"(hsum));
                    hw[i] = hrel;
                }
                acc[it] = __builtin_amdgcn_mfma_f32_16x16x32_f16(
                    __builtin_bit_cast(f16x8, hw), bfrag[ks], acc[it], 0, 0, 0);
            }
        }
        if (lm < 5) {
#pragma unroll
            for (int it = 0; it < 4; it++) {
                const int e0 = (w * 4 + it) * 16;
                float* op = out + ((size_t)slice * 1024 + e0 + lk * 4) * 5 + lm;
                op[0]  = acc[it][0] + bias;
                op[5]  = acc[it][1] + bias;
                op[10] = acc[it][2] + bias;
                op[15] = acc[it][3] + bias;
            }
        }
    }
}

// ---------------------------------------------------------------------------
extern "C" void kernel_launch(void* const* d_in, const int* in_sizes, int n_in,
                              void* d_out, int out_size, void* d_ws, size_t ws_size,
                              hipStream_t stream)
{
    const float* spikes = (const float*)d_in[0];
    const float* W_emb  = (const float*)d_in[1];
    const float* b_emb  = (const float*)d_in[2];
    const float* Ws1    = (const float*)d_in[3];
    const float* bs1    = (const float*)d_in[4];
    const float* Ws2    = (const float*)d_in[5];
    const float* bs2    = (const float*)d_in[6];
    const float* Wr1    = (const float*)d_in[7];
    const float* br1    = (const float*)d_in[8];
    const float* Wr2    = (const float*)d_in[9];
    const float* br2    = (const float*)d_in[10];
    const float* Wc1    = (const float*)d_in[11];
    const float* bc1    = (const float*)d_in[12];
    const float* Wc2    = (const float*)d_in[13];
    const float* bc2    = (const float*)d_in[14];
    const int*   se     = (const int*)d_in[15];
    const int*   re     = (const int*)d_in[16];

    float* out = (float*)d_out;
    float* ws  = (float*)d_ws;

    // workspace layout (float offsets, all 16B-aligned):
    float*          P     = ws;                                   // 73,440 f
    float*          bias1 = ws + 73440;                           // 256 f
    float*          bias2 = ws + 73696;                           // 256 f
    unsigned short* wg1f  = (unsigned short*)(ws + 73952);        // 8,192 u16
    unsigned short* wg2f  = (unsigned short*)(ws + 78048);        // 32,768 u16
    unsigned short* wg3fT = (unsigned short*)(ws + 94432);        // 73,728 u16
    unsigned short* wc2f  = (unsigned short*)(ws + 131296);       // 4,608 u16

    const dim3 blk(256);

    (void)hipFuncSetAttribute(reinterpret_cast<const void*>(final5),
                              hipFuncAttributeMaxDynamicSharedMemorySize, LDS_B2);

    prep_kernel<<<755, blk, 0, stream>>>(
        W_emb, b_emb, Ws1, bs1, Wr1, br1, Ws2, bs2, Wr2, br2, Wc1, bc1, Wc2,
        P, bias1, bias2, wg1f, wg2f, wg3fT, wc2f);

    // everything else fused per slice: h1 -> h2 -> S/R -> gather -> head
    final5<<<510, dim3(1024), LDS_B2, stream>>>(
        spikes, wg1f, bias1, wg2f, bias2, wg3fT, P, wc2f, bc2, se, re, out);
}